// Round 7
// baseline (596.710 us; speedup 1.0000x reference)
//
#include <hip/hip_runtime.h>
#include <math.h>

// Llama4 experts + shared LoRA (rank 8) — bf16 MFMA, 8-phase pipelined GEMMs.
// E=8, T=1024, H=1024, I=2048, F2=4096, R=8, scaling=2.
//
// R6->R7: ONLY change is __launch_bounds__(512) (was (512,2), which imposed a
// 128-VGPR cap -> 128-reg accumulator spilled to scratch: WRITE_SIZE 453MB vs
// 33MB expected, 300us. Flat WG size 512 already implies a 256-VGPR cap.)
//
//   convx      : xb = bf16(x)
//   transconv  : WguT bf16, gate/up interleaved at 32-col granularity
//   gemm1_8p   : hidden = SwiGLU(xb@WguT^T + 2*xa@Bgu^T)   [8-phase, 256x256]
//   gemm2_8p   : out = hidden@WdnT^T + 2*ha@Bdn^T          [8-phase, 256x128]
//
// 8-phase K-loop per K-tile (BK=64): 4 phases x {stage 1 half-tile of t+1,
// ds_read quadrant frags, raw s_barrier, lgkmcnt(0), setprio(1), 16(8) MFMA,
// setprio(0), barrier}. Counted vmcnt(2) once per K-tile. LDS XOR swizzle
// slot^=(row&7) on ds_read + pre-applied to the global source (linear LDS dest).

#define NE 8
#define TT 1024
#define HH 1024
#define II 2048
#define FF2 4096
#define RR 8
#define NROW (NE * TT)
#define SCAL 2.0f

typedef __bf16 bf16x8 __attribute__((ext_vector_type(8)));
typedef float f32x4 __attribute__((ext_vector_type(4)));

#define GLOAD16(g, l)                                                        \
  __builtin_amdgcn_global_load_lds((const __attribute__((address_space(1))) void*)(g), \
                                   (__attribute__((address_space(3))) void*)(l), 16, 0, 0)
#define BARRIER __builtin_amdgcn_s_barrier()
#define SB0 __builtin_amdgcn_sched_barrier(0)
#define WAITV2 asm volatile("s_waitcnt vmcnt(2)" ::: "memory")
#define WAITV0 asm volatile("s_waitcnt vmcnt(0)" ::: "memory")
#define WAITL0 asm volatile("s_waitcnt lgkmcnt(0)" ::: "memory")

__device__ __forceinline__ unsigned short f2bf(float f) {
  unsigned int u = __float_as_uint(f);
  u += 0x7fffu + ((u >> 16) & 1u);  // RNE
  return (unsigned short)(u >> 16);
}
__device__ __forceinline__ float dot4(float4 a, float4 b) {
  return a.x * b.x + a.y * b.y + a.z * b.z + a.w * b.w;
}

// ---------------- conversion pre-passes -------------------------------------
__global__ __launch_bounds__(256) void convx_kernel(const float* __restrict__ x,
                                                    unsigned short* __restrict__ xb) {
  const int i = blockIdx.x * 256 + threadIdx.x;
  const float4 a = *(const float4*)(x + (size_t)i * 8);
  const float4 b = *(const float4*)(x + (size_t)i * 8 + 4);
  union { unsigned short u[8]; uint4 v; } pk;
  pk.u[0] = f2bf(a.x); pk.u[1] = f2bf(a.y); pk.u[2] = f2bf(a.z); pk.u[3] = f2bf(a.w);
  pk.u[4] = f2bf(b.x); pk.u[5] = f2bf(b.y); pk.u[6] = f2bf(b.z); pk.u[7] = f2bf(b.w);
  *(uint4*)(xb + (size_t)i * 8) = pk.v;
}

// Wgu [e][1024][4096] f32 -> WguT [e][4096][1024] bf16, 32-granular interleave.
__global__ __launch_bounds__(256) void transconv_gu_kernel(const float* __restrict__ W,
                                                           unsigned short* __restrict__ WT) {
  __shared__ float ts[64][65];
  const int bid = blockIdx.x;           // 8*16*64
  const int nt = bid & 63, kt = (bid >> 6) & 15, e = bid >> 10;
  const float* Win = W + (size_t)e * HH * FF2 + (size_t)(kt * 64) * FF2 + nt * 64;
  const int tid = threadIdx.x;
#pragma unroll
  for (int l = 0; l < 4; ++l) {
    const int idx = tid + l * 256, r = idx >> 4, c4 = idx & 15;
    const float4 v = *(const float4*)(Win + (size_t)r * FF2 + c4 * 4);
    ts[r][c4 * 4 + 0] = v.x; ts[r][c4 * 4 + 1] = v.y;
    ts[r][c4 * 4 + 2] = v.z; ts[r][c4 * 4 + 3] = v.w;
  }
  __syncthreads();
  unsigned short* We = WT + (size_t)e * FF2 * HH;
#pragma unroll
  for (int l = 0; l < 2; ++l) {
    const int idx = tid + l * 256, j = idx >> 3, q = idx & 7;
    int orow;
    if (nt < 32) orow = (nt * 2 + (j >> 5)) * 64 + (j & 31);
    else         orow = ((nt - 32) * 2 + (j >> 5)) * 64 + 32 + (j & 31);
    union { unsigned short u[8]; uint4 v; } pk;
#pragma unroll
    for (int kk = 0; kk < 8; ++kk) pk.u[kk] = f2bf(ts[q * 8 + kk][j]);
    *(uint4*)(We + (size_t)orow * HH + kt * 64 + q * 8) = pk.v;
  }
}

// Wdn [e][2048][1024] f32 -> WdnT [e][1024][2048] bf16 (plain transpose).
__global__ __launch_bounds__(256) void transconv_dn_kernel(const float* __restrict__ W,
                                                           unsigned short* __restrict__ WT) {
  __shared__ float ts[64][65];
  const int bid = blockIdx.x;           // 8*32*16
  const int nt = bid & 15, kt = (bid >> 4) & 31, e = bid >> 9;
  const float* Win = W + (size_t)e * II * HH + (size_t)(kt * 64) * HH + nt * 64;
  const int tid = threadIdx.x;
#pragma unroll
  for (int l = 0; l < 4; ++l) {
    const int idx = tid + l * 256, r = idx >> 4, c4 = idx & 15;
    const float4 v = *(const float4*)(Win + (size_t)r * HH + c4 * 4);
    ts[r][c4 * 4 + 0] = v.x; ts[r][c4 * 4 + 1] = v.y;
    ts[r][c4 * 4 + 2] = v.z; ts[r][c4 * 4 + 3] = v.w;
  }
  __syncthreads();
  unsigned short* Wout = WT + (size_t)e * HH * II + (size_t)(nt * 64) * II + kt * 64;
#pragma unroll
  for (int l = 0; l < 2; ++l) {
    const int idx = tid + l * 256, j = idx >> 3, q = idx & 7;
    union { unsigned short u[8]; uint4 v; } pk;
#pragma unroll
    for (int kk = 0; kk < 8; ++kk) pk.u[kk] = f2bf(ts[q * 8 + kk][j]);
    *(uint4*)(Wout + (size_t)j * II + q * 8) = pk.v;
  }
}

// ---------------- rank-8 row dots -------------------------------------------
template <int K>
__global__ __launch_bounds__(256) void rowdot_kernel(const float* __restrict__ x,
                                                     const float* __restrict__ A,
                                                     float* __restrict__ xa) {
  const int w = threadIdx.x >> 6, lane = threadIdx.x & 63;
  const int t = blockIdx.x * 4 + w;
  const float* xrow = x + (size_t)t * K;
  float acc[RR];
#pragma unroll
  for (int r = 0; r < RR; ++r) acc[r] = 0.f;
#pragma unroll
  for (int c = 0; c < K / 256; ++c) {
    const float4 xv = *(const float4*)(xrow + c * 256 + lane * 4);
#pragma unroll
    for (int r = 0; r < RR; ++r) {
      const float4 av = *(const float4*)(A + (size_t)r * K + c * 256 + lane * 4);
      acc[r] += dot4(xv, av);
    }
  }
#pragma unroll
  for (int r = 0; r < RR; ++r) {
    float v = acc[r];
#pragma unroll
    for (int off = 32; off > 0; off >>= 1) v += __shfl_down(v, off, 64);
    if (lane == 0) xa[(size_t)t * RR + r] = v;
  }
}

__global__ __launch_bounds__(256) void rowdot_bf16_kernel(const unsigned short* __restrict__ h,
                                                          const float* __restrict__ A,
                                                          float* __restrict__ ha) {
  const int w = threadIdx.x >> 6, lane = threadIdx.x & 63;
  const int t = blockIdx.x * 4 + w;
  const unsigned short* hrow = h + (size_t)t * II;
  float acc[RR];
#pragma unroll
  for (int r = 0; r < RR; ++r) acc[r] = 0.f;
#pragma unroll
  for (int c = 0; c < II / 512; ++c) {
    const uint4 v = *(const uint4*)(hrow + c * 512 + lane * 8);
    float xv[8];
    xv[0] = __uint_as_float(v.x << 16); xv[1] = __uint_as_float(v.x & 0xffff0000u);
    xv[2] = __uint_as_float(v.y << 16); xv[3] = __uint_as_float(v.y & 0xffff0000u);
    xv[4] = __uint_as_float(v.z << 16); xv[5] = __uint_as_float(v.z & 0xffff0000u);
    xv[6] = __uint_as_float(v.w << 16); xv[7] = __uint_as_float(v.w & 0xffff0000u);
#pragma unroll
    for (int r = 0; r < RR; ++r) {
      const float4 a0 = *(const float4*)(A + (size_t)r * II + c * 512 + lane * 8);
      const float4 a1 = *(const float4*)(A + (size_t)r * II + c * 512 + lane * 8 + 4);
      acc[r] += xv[0] * a0.x + xv[1] * a0.y + xv[2] * a0.z + xv[3] * a0.w +
                xv[4] * a1.x + xv[5] * a1.y + xv[6] * a1.z + xv[7] * a1.w;
    }
  }
#pragma unroll
  for (int r = 0; r < RR; ++r) {
    float v = acc[r];
#pragma unroll
    for (int off = 32; off > 0; off >>= 1) v += __shfl_down(v, off, 64);
    if (lane == 0) ha[(size_t)t * RR + r] = v;
  }
}

// ---------------- gemm1_8p: 256x256, BK=64, 8 waves, dbuf+swizzle ----------
__global__ __launch_bounds__(512) void gemm1_8p_kernel(
    const unsigned short* __restrict__ xb, const unsigned short* __restrict__ WguT,
    const float* __restrict__ xa, const float* __restrict__ Bgu,
    unsigned short* __restrict__ hidden) {
  __shared__ unsigned short sm[2][2][256 * 64];  // [buf][A/B], 128 KB

  const int bid = blockIdx.x;          // 8e * 4tt * 16it
  const int e = bid >> 6, tt = (bid >> 4) & 3, it = bid & 15;
  const int t0 = e * TT + tt * 256;
  const unsigned short* Ag = xb + (size_t)t0 * HH;
  const unsigned short* Bg = WguT + (size_t)e * FF2 * HH + (size_t)(it * 256) * HH;

  const int tid = threadIdx.x;
  const int w = tid >> 6, lane = tid & 63;
  const int wr = w >> 2, wc = w & 3;          // 2M x 4N waves
  const int lrow = lane & 15, lkg = lane >> 4;  // k-group 0..3

  // staging: half h (128 rows) of K-tile kt into buf; linear LDS dest,
  // inverse-swizzled global source (slot ^= row&7).
  auto stageA = [&](int buf, int kt, int h) {
#pragma unroll
    for (int l = 0; l < 2; ++l) {
      const int i = tid + l * 512;
      const int r = i >> 3, sl = i & 7;
      const int row = h * 128 + r;
      GLOAD16((const char*)(Ag + (size_t)row * HH + kt * 64 + ((sl ^ (r & 7)) << 3)),
              (char*)&sm[buf][0][0] + row * 128 + sl * 16);
    }
  };
  auto stageB = [&](int buf, int kt, int h) {
#pragma unroll
    for (int l = 0; l < 2; ++l) {
      const int i = tid + l * 512;
      const int r = i >> 3, sl = i & 7;
      const int row = h * 128 + r;
      GLOAD16((const char*)(Bg + (size_t)row * HH + kt * 64 + ((sl ^ (r & 7)) << 3)),
              (char*)&sm[buf][1][0] + row * 128 + sl * 16);
    }
  };
  auto ldA = [&](int p, int mIdx, int s) -> bf16x8 {
    const int row = wr * 128 + mIdx * 16 + lrow;
    const int sl = (s * 4 + lkg) ^ (row & 7);
    return *(const bf16x8*)((const char*)&sm[p][0][0] + row * 128 + sl * 16);
  };
  auto ldB = [&](int p, int f, int s) -> bf16x8 {
    const int row = wc * 64 + f * 16 + lrow;
    const int sl = (s * 4 + lkg) ^ (row & 7);
    return *(const bf16x8*)((const char*)&sm[p][1][0] + row * 128 + sl * 16);
  };

  f32x4 acc[8][4];
#pragma unroll
  for (int i = 0; i < 8; ++i)
#pragma unroll
    for (int j = 0; j < 4; ++j) acc[i][j] = (f32x4)(0.f);

  // prologue: stage all of tile 0 into buf 0
  stageA(0, 0, 0); stageA(0, 0, 1); stageB(0, 0, 0); stageB(0, 0, 1);

  bf16x8 af[4][2], bfr[2][2];
  const int NT = HH / 64;  // 16
  for (int t = 0; t < NT; ++t) {
    const int p = t & 1, q = p ^ 1;
    const bool pf = (t + 1 < NT);
    // ---- phase 0: quadrant (mh0, nh0)
    if (pf) { stageA(q, t + 1, 0); WAITV2; } else { WAITV0; }
    SB0; BARRIER;
#pragma unroll
    for (int mi = 0; mi < 4; ++mi) { af[mi][0] = ldA(p, mi, 0); af[mi][1] = ldA(p, mi, 1); }
#pragma unroll
    for (int nj = 0; nj < 2; ++nj) { bfr[nj][0] = ldB(p, nj, 0); bfr[nj][1] = ldB(p, nj, 1); }
    BARRIER; WAITL0; SB0;
    __builtin_amdgcn_s_setprio(1);
#pragma unroll
    for (int mi = 0; mi < 4; ++mi)
#pragma unroll
      for (int nj = 0; nj < 2; ++nj)
#pragma unroll
        for (int s = 0; s < 2; ++s)
          acc[mi][nj] = __builtin_amdgcn_mfma_f32_16x16x32_bf16(af[mi][s], bfr[nj][s], acc[mi][nj], 0, 0, 0);
    __builtin_amdgcn_s_setprio(0); SB0; BARRIER;
    // ---- phase 1: (mh0, nh1)
    if (pf) stageA(q, t + 1, 1);
#pragma unroll
    for (int nj = 0; nj < 2; ++nj) { bfr[nj][0] = ldB(p, 2 + nj, 0); bfr[nj][1] = ldB(p, 2 + nj, 1); }
    BARRIER; WAITL0; SB0;
    __builtin_amdgcn_s_setprio(1);
#pragma unroll
    for (int mi = 0; mi < 4; ++mi)
#pragma unroll
      for (int nj = 0; nj < 2; ++nj)
#pragma unroll
        for (int s = 0; s < 2; ++s)
          acc[mi][2 + nj] = __builtin_amdgcn_mfma_f32_16x16x32_bf16(af[mi][s], bfr[nj][s], acc[mi][2 + nj], 0, 0, 0);
    __builtin_amdgcn_s_setprio(0); SB0; BARRIER;
    // ---- phase 2: (mh1, nh1)
    if (pf) stageB(q, t + 1, 0);
#pragma unroll
    for (int mi = 0; mi < 4; ++mi) { af[mi][0] = ldA(p, 4 + mi, 0); af[mi][1] = ldA(p, 4 + mi, 1); }
    BARRIER; WAITL0; SB0;
    __builtin_amdgcn_s_setprio(1);
#pragma unroll
    for (int mi = 0; mi < 4; ++mi)
#pragma unroll
      for (int nj = 0; nj < 2; ++nj)
#pragma unroll
        for (int s = 0; s < 2; ++s)
          acc[4 + mi][2 + nj] = __builtin_amdgcn_mfma_f32_16x16x32_bf16(af[mi][s], bfr[nj][s], acc[4 + mi][2 + nj], 0, 0, 0);
    __builtin_amdgcn_s_setprio(0); SB0; BARRIER;
    // ---- phase 3: (mh1, nh0)
    if (pf) stageB(q, t + 1, 1);
#pragma unroll
    for (int nj = 0; nj < 2; ++nj) { bfr[nj][0] = ldB(p, nj, 0); bfr[nj][1] = ldB(p, nj, 1); }
    BARRIER; WAITL0; SB0;
    __builtin_amdgcn_s_setprio(1);
#pragma unroll
    for (int mi = 0; mi < 4; ++mi)
#pragma unroll
      for (int nj = 0; nj < 2; ++nj)
#pragma unroll
        for (int s = 0; s < 2; ++s)
          acc[4 + mi][nj] = __builtin_amdgcn_mfma_f32_16x16x32_bf16(af[mi][s], bfr[nj][s], acc[4 + mi][nj], 0, 0, 0);
    __builtin_amdgcn_s_setprio(0); SB0; BARRIER;
  }

  // epilogue: LoRA + SwiGLU, bf16 store
  const float4* xa4 = (const float4*)xa;
  const float4* B4 = (const float4*)Bgu;
  const int bblk = it * 4 + wc;  // 64-row block of WguT = 32 gate + 32 up cols
#pragma unroll
  for (int f = 0; f < 2; ++f) {
    const int g = bblk * 32 + f * 16 + lrow;  // hidden col
    const float4 bg0 = B4[g * 2], bg1 = B4[g * 2 + 1];
    const float4 bu0 = B4[(II + g) * 2], bu1 = B4[(II + g) * 2 + 1];
#pragma unroll
    for (int m = 0; m < 8; ++m) {
      const int tb = t0 + wr * 128 + m * 16 + lkg * 4;
#pragma unroll
      for (int j = 0; j < 4; ++j) {
        const int trow = tb + j;
        const float4 xr0 = xa4[trow * 2], xr1 = xa4[trow * 2 + 1];
        const float gv = acc[m][f][j] + SCAL * (dot4(xr0, bg0) + dot4(xr1, bg1));
        const float uv = acc[m][f + 2][j] + SCAL * (dot4(xr0, bu0) + dot4(xr1, bu1));
        const float s = gv / (1.f + __expf(-gv));
        hidden[(size_t)trow * II + g] = f2bf(uv * s);
      }
    }
  }
}

// ---------------- gemm2_8p: 256x128, BK=64, 8 waves, dbuf+swizzle ----------
__global__ __launch_bounds__(512) void gemm2_8p_kernel(
    const unsigned short* __restrict__ hid, const unsigned short* __restrict__ WdnT,
    const float* __restrict__ ha, const float* __restrict__ Bdn,
    float* __restrict__ out) {
  __shared__ unsigned short sm[2][24576];  // A 256x64 @0, B 128x64 @16384; 96 KB

  const int bid = blockIdx.x;          // 8e * 4tt * 8ht
  const int e = bid >> 5, tt = (bid >> 3) & 3, ht = bid & 7;
  const int t0 = e * TT + tt * 256;
  const int h0 = ht * 128;
  const unsigned short* Ag = hid + (size_t)t0 * II;
  const unsigned short* Bg = WdnT + (size_t)e * HH * II + (size_t)h0 * II;

  const int tid = threadIdx.x;
  const int w = tid >> 6, lane = tid & 63;
  const int wr = w >> 2, wc = w & 3;
  const int lrow = lane & 15, lkg = lane >> 4;

  auto stageA = [&](int buf, int kt, int h) {
#pragma unroll
    for (int l = 0; l < 2; ++l) {
      const int i = tid + l * 512;
      const int r = i >> 3, sl = i & 7;
      const int row = h * 128 + r;
      GLOAD16((const char*)(Ag + (size_t)row * II + kt * 64 + ((sl ^ (r & 7)) << 3)),
              (char*)&sm[buf][0] + row * 128 + sl * 16);
    }
  };
  auto stageB = [&](int buf, int kt) {
#pragma unroll
    for (int l = 0; l < 2; ++l) {
      const int i = tid + l * 512;
      const int r = i >> 3, sl = i & 7;
      GLOAD16((const char*)(Bg + (size_t)r * II + kt * 64 + ((sl ^ (r & 7)) << 3)),
              (char*)&sm[buf][16384] + r * 128 + sl * 16);
    }
  };
  auto ldA = [&](int p, int mIdx, int s) -> bf16x8 {
    const int row = wr * 128 + mIdx * 16 + lrow;
    const int sl = (s * 4 + lkg) ^ (row & 7);
    return *(const bf16x8*)((const char*)&sm[p][0] + row * 128 + sl * 16);
  };
  auto ldB = [&](int p, int nj, int s) -> bf16x8 {
    const int row = wc * 32 + nj * 16 + lrow;
    const int sl = (s * 4 + lkg) ^ (row & 7);
    return *(const bf16x8*)((const char*)&sm[p][16384] + row * 128 + sl * 16);
  };

  f32x4 acc[8][2];
#pragma unroll
  for (int i = 0; i < 8; ++i)
#pragma unroll
    for (int j = 0; j < 2; ++j) acc[i][j] = (f32x4)(0.f);

  stageA(0, 0, 0); stageA(0, 0, 1); stageB(0, 0);

  bf16x8 af[2][2], bfr[2][2];
  const int NT = II / 64;  // 32
  for (int t = 0; t < NT; ++t) {
    const int p = t & 1, q = p ^ 1;
    const bool pf = (t + 1 < NT);
    // ---- phase 0: mq0 (+ B read)
    if (pf) { stageA(q, t + 1, 0); WAITV2; } else { WAITV0; }
    SB0; BARRIER;
#pragma unroll
    for (int nj = 0; nj < 2; ++nj) { bfr[nj][0] = ldB(p, nj, 0); bfr[nj][1] = ldB(p, nj, 1); }
#pragma unroll
    for (int mi = 0; mi < 2; ++mi) { af[mi][0] = ldA(p, mi, 0); af[mi][1] = ldA(p, mi, 1); }
    BARRIER; WAITL0; SB0;
    __builtin_amdgcn_s_setprio(1);
#pragma unroll
    for (int mi = 0; mi < 2; ++mi)
#pragma unroll
      for (int nj = 0; nj < 2; ++nj)
#pragma unroll
        for (int s = 0; s < 2; ++s)
          acc[mi][nj] = __builtin_amdgcn_mfma_f32_16x16x32_bf16(af[mi][s], bfr[nj][s], acc[mi][nj], 0, 0, 0);
    __builtin_amdgcn_s_setprio(0); SB0; BARRIER;
    // ---- phases 1..3: mq1..mq3
#pragma unroll
    for (int mq = 1; mq < 4; ++mq) {
      if (pf) {
        if (mq == 1) stageA(q, t + 1, 1);
        else if (mq == 2) stageB(q, t + 1);
      }
#pragma unroll
      for (int mi = 0; mi < 2; ++mi) { af[mi][0] = ldA(p, mq * 2 + mi, 0); af[mi][1] = ldA(p, mq * 2 + mi, 1); }
      BARRIER; WAITL0; SB0;
      __builtin_amdgcn_s_setprio(1);
#pragma unroll
      for (int mi = 0; mi < 2; ++mi)
#pragma unroll
        for (int nj = 0; nj < 2; ++nj)
#pragma unroll
          for (int s = 0; s < 2; ++s)
            acc[mq * 2 + mi][nj] = __builtin_amdgcn_mfma_f32_16x16x32_bf16(af[mi][s], bfr[nj][s], acc[mq * 2 + mi][nj], 0, 0, 0);
      __builtin_amdgcn_s_setprio(0); SB0; BARRIER;
    }
  }

  const float4* ha4 = (const float4*)ha;
  const float4* B4 = (const float4*)Bdn;
#pragma unroll
  for (int nj = 0; nj < 2; ++nj) {
    const int col = h0 + wc * 32 + nj * 16 + lrow;
    const float4 b0 = B4[col * 2], b1 = B4[col * 2 + 1];
#pragma unroll
    for (int m = 0; m < 8; ++m) {
      const int tb = t0 + wr * 128 + m * 16 + lkg * 4;
#pragma unroll
      for (int j = 0; j < 4; ++j) {
        const int trow = tb + j;
        const float4 hr0 = ha4[trow * 2], hr1 = ha4[trow * 2 + 1];
        out[(size_t)trow * HH + col] = acc[m][nj][j] + SCAL * (dot4(hr0, b0) + dot4(hr1, b1));
      }
    }
  }
}

// ---------------- fallback (R3): in-loop conversion GEMMs -------------------
__global__ __launch_bounds__(256) void gemm1_conv_kernel(const float* __restrict__ x,
                                                         const float* __restrict__ Wgu,
                                                         const float* __restrict__ xa,
                                                         const float* __restrict__ Bgu,
                                                         unsigned short* __restrict__ hidden) {
  __shared__ unsigned short As[128][40];
  __shared__ unsigned short Bs[128][40];
  const int bid = blockIdx.x;
  const int e = bid >> 8, rem = bid & 255, tt = rem >> 5, it = rem & 31;
  const int t0 = e * TT + tt * 128, i0 = it * 64;
  const float* Wg = Wgu + (size_t)e * HH * FF2;
  const int tid = threadIdx.x, w = tid >> 6, lane = tid & 63;
  const int wr = w >> 1, wc = w & 1, lrow = lane & 15, lk = (lane >> 4) * 8;
  f32x4 acc[4][4];
#pragma unroll
  for (int i = 0; i < 4; ++i)
#pragma unroll
    for (int j = 0; j < 4; ++j) acc[i][j] = (f32x4)(0.f);
  for (int k0 = 0; k0 < HH; k0 += 32) {
#pragma unroll
    for (int l = 0; l < 4; ++l) {
      const int idx = tid + l * 256, row = idx >> 3, kq = idx & 7;
      const float4 v = *(const float4*)(x + (size_t)(t0 + row) * HH + k0 + kq * 4);
      ushort4 p; p.x = f2bf(v.x); p.y = f2bf(v.y); p.z = f2bf(v.z); p.w = f2bf(v.w);
      *(ushort4*)&As[row][kq * 4] = p;
    }
#pragma unroll
    for (int l = 0; l < 2; ++l) {
      const int idx = tid + l * 256, col = idx & 127, kq8 = idx >> 7;
      const int gcol = i0 + (col & 63) + ((col >> 6) * II);
      union { unsigned short u[8]; uint4 v; } pk;
#pragma unroll
      for (int kk = 0; kk < 8; ++kk) pk.u[kk] = f2bf(Wg[(size_t)(k0 + kq8 * 8 + kk) * FF2 + gcol]);
      *(uint4*)&Bs[col][kq8 * 8] = pk.v;
    }
    __syncthreads();
    bf16x8 af[4], bfr[4];
#pragma unroll
    for (int mi = 0; mi < 4; ++mi) af[mi] = *(const bf16x8*)&As[wr * 64 + mi * 16 + lrow][lk];
#pragma unroll
    for (int nj = 0; nj < 4; ++nj) {
      const int c = (nj < 2) ? (wc * 32 + nj * 16) : (64 + wc * 32 + (nj - 2) * 16);
      bfr[nj] = *(const bf16x8*)&Bs[c + lrow][lk];
    }
#pragma unroll
    for (int mi = 0; mi < 4; ++mi)
#pragma unroll
      for (int nj = 0; nj < 4; ++nj)
        acc[mi][nj] = __builtin_amdgcn_mfma_f32_16x16x32_bf16(af[mi], bfr[nj], acc[mi][nj], 0, 0, 0);
    __syncthreads();
  }
  const float4* xa4 = (const float4*)xa;
  const float4* B4 = (const float4*)Bgu;
#pragma unroll
  for (int nj = 0; nj < 2; ++nj) {
    const int coln = i0 + wc * 32 + nj * 16 + lrow;
    const float4 bg0 = B4[coln * 2], bg1 = B4[coln * 2 + 1];
    const float4 bu0 = B4[(II + coln) * 2], bu1 = B4[(II + coln) * 2 + 1];
#pragma unroll
    for (int mi = 0; mi < 4; ++mi) {
      const int tb = t0 + wr * 64 + mi * 16 + (lane >> 4) * 4;
#pragma unroll
      for (int j = 0; j < 4; ++j) {
        const int t = tb + j;
        const float4 xr0 = xa4[t * 2], xr1 = xa4[t * 2 + 1];
        const float g = acc[mi][nj][j] + SCAL * (dot4(xr0, bg0) + dot4(xr1, bg1));
        const float u = acc[mi][nj + 2][j] + SCAL * (dot4(xr0, bu0) + dot4(xr1, bu1));
        const float s = g / (1.f + __expf(-g));
        hidden[(size_t)t * II + coln] = f2bf(u * s);
      }
    }
  }
}

__global__ __launch_bounds__(256) void gemm2_conv_kernel(const unsigned short* __restrict__ hid,
                                                         const float* __restrict__ Wdn,
                                                         const float* __restrict__ ha,
                                                         const float* __restrict__ Bdn,
                                                         float* __restrict__ out) {
  __shared__ unsigned short As[128][40];
  __shared__ unsigned short Bs[128][40];
  const int bid = blockIdx.x;
  const int e = bid >> 6, rem = bid & 63, tt = rem >> 3, ht = rem & 7;
  const int t0 = e * TT + tt * 128, h0 = ht * 128;
  const float* Wd = Wdn + (size_t)e * II * HH;
  const int tid = threadIdx.x, w = tid >> 6, lane = tid & 63;
  const int wr = w >> 1, wc = w & 1, lrow = lane & 15, lk = (lane >> 4) * 8;
  f32x4 acc[4][4];
#pragma unroll
  for (int i = 0; i < 4; ++i)
#pragma unroll
    for (int j = 0; j < 4; ++j) acc[i][j] = (f32x4)(0.f);
  for (int k0 = 0; k0 < II; k0 += 32) {
#pragma unroll
    for (int l = 0; l < 2; ++l) {
      const int idx = tid + l * 256, row = idx >> 2, kq8 = idx & 3;
      *(uint4*)&As[row][kq8 * 8] = *(const uint4*)(hid + (size_t)(t0 + row) * II + k0 + kq8 * 8);
    }
#pragma unroll
    for (int l = 0; l < 2; ++l) {
      const int idx = tid + l * 256, col = idx & 127, kq8 = idx >> 7;
      union { unsigned short u[8]; uint4 v; } pk;
#pragma unroll
      for (int kk = 0; kk < 8; ++kk) pk.u[kk] = f2bf(Wd[(size_t)(k0 + kq8 * 8 + kk) * HH + h0 + col]);
      *(uint4*)&Bs[col][kq8 * 8] = pk.v;
    }
    __syncthreads();
    bf16x8 af[4], bfr[4];
#pragma unroll
    for (int mi = 0; mi < 4; ++mi) af[mi] = *(const bf16x8*)&As[wr * 64 + mi * 16 + lrow][lk];
#pragma unroll
    for (int nj = 0; nj < 4; ++nj) bfr[nj] = *(const bf16x8*)&Bs[wc * 64 + nj * 16 + lrow][lk];
#pragma unroll
    for (int mi = 0; mi < 4; ++mi)
#pragma unroll
      for (int nj = 0; nj < 4; ++nj)
        acc[mi][nj] = __builtin_amdgcn_mfma_f32_16x16x32_bf16(af[mi], bfr[nj], acc[mi][nj], 0, 0, 0);
    __syncthreads();
  }
  const float4* ha4 = (const float4*)ha;
  const float4* B4 = (const float4*)Bdn;
#pragma unroll
  for (int nj = 0; nj < 4; ++nj) {
    const int coln = h0 + wc * 64 + nj * 16 + lrow;
    const float4 b0 = B4[coln * 2], b1 = B4[coln * 2 + 1];
#pragma unroll
    for (int mi = 0; mi < 4; ++mi) {
      const int tb = t0 + wr * 64 + mi * 16 + (lane >> 4) * 4;
#pragma unroll
      for (int j = 0; j < 4; ++j) {
        const int t = tb + j;
        const float4 hr0 = ha4[t * 2], hr1 = ha4[t * 2 + 1];
        out[(size_t)t * HH + coln] = acc[mi][nj][j] + SCAL * (dot4(hr0, b0) + dot4(hr1, b1));
      }
    }
  }
}

extern "C" void kernel_launch(void* const* d_in, const int* in_sizes, int n_in,
                              void* d_out, int out_size, void* d_ws, size_t ws_size,
                              hipStream_t stream) {
  const float* x   = (const float*)d_in[0];
  const float* Wgu = (const float*)d_in[1];
  const float* Wdn = (const float*)d_in[2];
  const float* Agu = (const float*)d_in[3];
  const float* Bgu = (const float*)d_in[4];
  const float* Adn = (const float*)d_in[5];
  const float* Bdn = (const float*)d_in[6];
  float* out = (float*)d_out;

  char* ws = (char*)d_ws;
  unsigned short* hidden = (unsigned short*)ws;                      //  32 MB
  const size_t OFF_XB  = (size_t)NROW * II * 2;                      //  32 MB
  const size_t OFF_WGU = OFF_XB + (size_t)NROW * HH * 2;             //  48 MB
  const size_t OFF_WDN = OFF_WGU + (size_t)NE * FF2 * HH * 2;        // 112 MB
  const size_t OFF_XA  = OFF_WDN + (size_t)NE * HH * II * 2;         // 144 MB
  const size_t OFF_HA  = OFF_XA + (size_t)NROW * RR * 4;
  const size_t NEED    = OFF_HA + (size_t)NROW * RR * 4;

  if (ws_size >= NEED) {
    unsigned short* xb   = (unsigned short*)(ws + OFF_XB);
    unsigned short* WguT = (unsigned short*)(ws + OFF_WGU);
    unsigned short* WdnT = (unsigned short*)(ws + OFF_WDN);
    float* xa = (float*)(ws + OFF_XA);
    float* ha = (float*)(ws + OFF_HA);

    convx_kernel<<<(NROW * HH) / (256 * 8), 256, 0, stream>>>(x, xb);
    transconv_gu_kernel<<<NE * 16 * 64, 256, 0, stream>>>(Wgu, WguT);
    transconv_dn_kernel<<<NE * 32 * 16, 256, 0, stream>>>(Wdn, WdnT);
    rowdot_kernel<HH><<<NROW / 4, 256, 0, stream>>>(x, Agu, xa);
    gemm1_8p_kernel<<<NE * 4 * 16, 512, 0, stream>>>(xb, WguT, xa, Bgu, hidden);
    rowdot_bf16_kernel<<<NROW / 4, 256, 0, stream>>>(hidden, Adn, ha);
    gemm2_8p_kernel<<<NE * 4 * 8, 512, 0, stream>>>(hidden, WdnT, ha, Bdn, out);
  } else {
    float* xa = (float*)(ws + OFF_XB);
    float* ha = xa + (size_t)NROW * RR;
    rowdot_kernel<HH><<<NROW / 4, 256, 0, stream>>>(x, Agu, xa);
    gemm1_conv_kernel<<<NE * 8 * 32, 256, 0, stream>>>(x, Wgu, xa, Bgu, hidden);
    rowdot_bf16_kernel<<<NROW / 4, 256, 0, stream>>>(hidden, Adn, ha);
    gemm2_conv_kernel<<<NE * 8 * 8, 256, 0, stream>>>(hidden, Wdn, ha, Bdn, out);
  }
}

// Round 9
// 399.289 us; speedup vs baseline: 1.4944x; 1.4944x over previous
//
#include <hip/hip_runtime.h>
#include <math.h>

// Llama4 experts + shared LoRA (rank 8) — bf16 MFMA, 8-phase pipelined GEMMs.
// E=8, T=1024, H=1024, I=2048, F2=4096, R=8, scaling=2.
//
// R8 (resubmitted after infra failure): gemm1 tile 256x256 -> 256x128 (acc 128
// f32 -> 64 f32/thread) to fit the observed 128-VGPR allocation for 512-thread
// WGs (R6/R7: acc spilled, WRITE_SIZE 453MB vs 33MB, 280us). WguT interleave
// 16-col granular so each wave holds gate+up frags for the same 16 hidden cols
// (nj=0 gate, nj=1 up). __launch_bounds__(512,1) to (maybe) lift the cap.
//
// 8-phase K-loop per K-tile (BK=64), counted vmcnt(2), raw s_barrier,
// setprio around MFMA, XOR slot-swizzle (both-sides: pre-swizzled global
// source for global_load_lds + swizzled ds_read).

#define NE 8
#define TT 1024
#define HH 1024
#define II 2048
#define FF2 4096
#define RR 8
#define NROW (NE * TT)
#define SCAL 2.0f

typedef __bf16 bf16x8 __attribute__((ext_vector_type(8)));
typedef float f32x4 __attribute__((ext_vector_type(4)));

#define GLOAD16(g, l)                                                        \
  __builtin_amdgcn_global_load_lds((const __attribute__((address_space(1))) void*)(g), \
                                   (__attribute__((address_space(3))) void*)(l), 16, 0, 0)
#define BARRIER __builtin_amdgcn_s_barrier()
#define SB0 __builtin_amdgcn_sched_barrier(0)
#define WAITV2 asm volatile("s_waitcnt vmcnt(2)" ::: "memory")
#define WAITV0 asm volatile("s_waitcnt vmcnt(0)" ::: "memory")
#define WAITL0 asm volatile("s_waitcnt lgkmcnt(0)" ::: "memory")

__device__ __forceinline__ unsigned short f2bf(float f) {
  unsigned int u = __float_as_uint(f);
  u += 0x7fffu + ((u >> 16) & 1u);  // RNE
  return (unsigned short)(u >> 16);
}
__device__ __forceinline__ float dot4(float4 a, float4 b) {
  return a.x * b.x + a.y * b.y + a.z * b.z + a.w * b.w;
}

// ---------------- conversion pre-passes -------------------------------------
__global__ __launch_bounds__(256) void convx_kernel(const float* __restrict__ x,
                                                    unsigned short* __restrict__ xb) {
  const int i = blockIdx.x * 256 + threadIdx.x;
  const float4 a = *(const float4*)(x + (size_t)i * 8);
  const float4 b = *(const float4*)(x + (size_t)i * 8 + 4);
  union { unsigned short u[8]; uint4 v; } pk;
  pk.u[0] = f2bf(a.x); pk.u[1] = f2bf(a.y); pk.u[2] = f2bf(a.z); pk.u[3] = f2bf(a.w);
  pk.u[4] = f2bf(b.x); pk.u[5] = f2bf(b.y); pk.u[6] = f2bf(b.z); pk.u[7] = f2bf(b.w);
  *(uint4*)(xb + (size_t)i * 8) = pk.v;
}

// Wgu [e][1024][4096] f32 -> WguT [e][4096][1024] bf16, 16-granular interleave:
// gate col gc -> row (gc>>4)*32 + (gc&15); up col uc -> row (uc>>4)*32+16+(uc&15).
__global__ __launch_bounds__(256) void transconv_gu_kernel(const float* __restrict__ W,
                                                           unsigned short* __restrict__ WT) {
  __shared__ float ts[64][65];
  const int bid = blockIdx.x;           // 8*16*64
  const int nt = bid & 63, kt = (bid >> 6) & 15, e = bid >> 10;
  const float* Win = W + (size_t)e * HH * FF2 + (size_t)(kt * 64) * FF2 + nt * 64;
  const int tid = threadIdx.x;
#pragma unroll
  for (int l = 0; l < 4; ++l) {
    const int idx = tid + l * 256, r = idx >> 4, c4 = idx & 15;
    const float4 v = *(const float4*)(Win + (size_t)r * FF2 + c4 * 4);
    ts[r][c4 * 4 + 0] = v.x; ts[r][c4 * 4 + 1] = v.y;
    ts[r][c4 * 4 + 2] = v.z; ts[r][c4 * 4 + 3] = v.w;
  }
  __syncthreads();
  unsigned short* We = WT + (size_t)e * FF2 * HH;
#pragma unroll
  for (int l = 0; l < 2; ++l) {
    const int idx = tid + l * 256, j = idx >> 3, q = idx & 7;
    int orow;
    if (nt < 32) orow = (nt * 4 + (j >> 4)) * 32 + (j & 15);             // gate
    else         orow = ((nt - 32) * 4 + (j >> 4)) * 32 + 16 + (j & 15); // up
    union { unsigned short u[8]; uint4 v; } pk;
#pragma unroll
    for (int kk = 0; kk < 8; ++kk) pk.u[kk] = f2bf(ts[q * 8 + kk][j]);
    *(uint4*)(We + (size_t)orow * HH + kt * 64 + q * 8) = pk.v;
  }
}

// Wdn [e][2048][1024] f32 -> WdnT [e][1024][2048] bf16 (plain transpose).
__global__ __launch_bounds__(256) void transconv_dn_kernel(const float* __restrict__ W,
                                                           unsigned short* __restrict__ WT) {
  __shared__ float ts[64][65];
  const int bid = blockIdx.x;           // 8*32*16
  const int nt = bid & 15, kt = (bid >> 4) & 31, e = bid >> 9;
  const float* Win = W + (size_t)e * II * HH + (size_t)(kt * 64) * HH + nt * 64;
  const int tid = threadIdx.x;
#pragma unroll
  for (int l = 0; l < 4; ++l) {
    const int idx = tid + l * 256, r = idx >> 4, c4 = idx & 15;
    const float4 v = *(const float4*)(Win + (size_t)r * HH + c4 * 4);
    ts[r][c4 * 4 + 0] = v.x; ts[r][c4 * 4 + 1] = v.y;
    ts[r][c4 * 4 + 2] = v.z; ts[r][c4 * 4 + 3] = v.w;
  }
  __syncthreads();
  unsigned short* Wout = WT + (size_t)e * HH * II + (size_t)(nt * 64) * II + kt * 64;
#pragma unroll
  for (int l = 0; l < 2; ++l) {
    const int idx = tid + l * 256, j = idx >> 3, q = idx & 7;
    union { unsigned short u[8]; uint4 v; } pk;
#pragma unroll
    for (int kk = 0; kk < 8; ++kk) pk.u[kk] = f2bf(ts[q * 8 + kk][j]);
    *(uint4*)(Wout + (size_t)j * II + q * 8) = pk.v;
  }
}

// ---------------- rank-8 row dots -------------------------------------------
template <int K>
__global__ __launch_bounds__(256) void rowdot_kernel(const float* __restrict__ x,
                                                     const float* __restrict__ A,
                                                     float* __restrict__ xa) {
  const int w = threadIdx.x >> 6, lane = threadIdx.x & 63;
  const int t = blockIdx.x * 4 + w;
  const float* xrow = x + (size_t)t * K;
  float acc[RR];
#pragma unroll
  for (int r = 0; r < RR; ++r) acc[r] = 0.f;
#pragma unroll
  for (int c = 0; c < K / 256; ++c) {
    const float4 xv = *(const float4*)(xrow + c * 256 + lane * 4);
#pragma unroll
    for (int r = 0; r < RR; ++r) {
      const float4 av = *(const float4*)(A + (size_t)r * K + c * 256 + lane * 4);
      acc[r] += dot4(xv, av);
    }
  }
#pragma unroll
  for (int r = 0; r < RR; ++r) {
    float v = acc[r];
#pragma unroll
    for (int off = 32; off > 0; off >>= 1) v += __shfl_down(v, off, 64);
    if (lane == 0) xa[(size_t)t * RR + r] = v;
  }
}

__global__ __launch_bounds__(256) void rowdot_bf16_kernel(const unsigned short* __restrict__ h,
                                                          const float* __restrict__ A,
                                                          float* __restrict__ ha) {
  const int w = threadIdx.x >> 6, lane = threadIdx.x & 63;
  const int t = blockIdx.x * 4 + w;
  const unsigned short* hrow = h + (size_t)t * II;
  float acc[RR];
#pragma unroll
  for (int r = 0; r < RR; ++r) acc[r] = 0.f;
#pragma unroll
  for (int c = 0; c < II / 512; ++c) {
    const uint4 v = *(const uint4*)(hrow + c * 512 + lane * 8);
    float xv[8];
    xv[0] = __uint_as_float(v.x << 16); xv[1] = __uint_as_float(v.x & 0xffff0000u);
    xv[2] = __uint_as_float(v.y << 16); xv[3] = __uint_as_float(v.y & 0xffff0000u);
    xv[4] = __uint_as_float(v.z << 16); xv[5] = __uint_as_float(v.z & 0xffff0000u);
    xv[6] = __uint_as_float(v.w << 16); xv[7] = __uint_as_float(v.w & 0xffff0000u);
#pragma unroll
    for (int r = 0; r < RR; ++r) {
      const float4 a0 = *(const float4*)(A + (size_t)r * II + c * 512 + lane * 8);
      const float4 a1 = *(const float4*)(A + (size_t)r * II + c * 512 + lane * 8 + 4);
      acc[r] += xv[0] * a0.x + xv[1] * a0.y + xv[2] * a0.z + xv[3] * a0.w +
                xv[4] * a1.x + xv[5] * a1.y + xv[6] * a1.z + xv[7] * a1.w;
    }
  }
#pragma unroll
  for (int r = 0; r < RR; ++r) {
    float v = acc[r];
#pragma unroll
    for (int off = 32; off > 0; off >>= 1) v += __shfl_down(v, off, 64);
    if (lane == 0) ha[(size_t)t * RR + r] = v;
  }
}

// ---------------- gemm1_8p: 256x128, BK=64, 8 waves (2Mx4N), dbuf+swizzle ---
// B panel = 128 WguT rows = 64 hidden cols (16-granular gate/up interleave).
// Wave wc owns B rows [wc*32, wc*32+32): nj=0 gate frag, nj=1 up frag, same
// 16 hidden cols. acc[8][2] = 64 f32/thread (fits 128-VGPR allocation).
__global__ __launch_bounds__(512, 1) void gemm1_8p_kernel(
    const unsigned short* __restrict__ xb, const unsigned short* __restrict__ WguT,
    const float* __restrict__ xa, const float* __restrict__ Bgu,
    unsigned short* __restrict__ hidden) {
  __shared__ unsigned short sm[2][24576];  // A 256x64 @0, B 128x64 @16384; 96 KB

  const int bid = blockIdx.x;          // 8e * 4tt * 32it
  const int e = bid >> 7, tt = (bid >> 5) & 3, it = bid & 31;
  const int t0 = e * TT + tt * 256;
  const unsigned short* Ag = xb + (size_t)t0 * HH;
  const unsigned short* Bg = WguT + (size_t)e * FF2 * HH + (size_t)(it * 128) * HH;

  const int tid = threadIdx.x;
  const int w = tid >> 6, lane = tid & 63;
  const int wr = w >> 2, wc = w & 3;
  const int lrow = lane & 15, lkg = lane >> 4;

  auto stageA = [&](int buf, int kt, int h) {
#pragma unroll
    for (int l = 0; l < 2; ++l) {
      const int i = tid + l * 512;
      const int r = i >> 3, sl = i & 7;
      const int row = h * 128 + r;
      GLOAD16((const char*)(Ag + (size_t)row * HH + kt * 64 + ((sl ^ (r & 7)) << 3)),
              (char*)&sm[buf][0] + row * 128 + sl * 16);
    }
  };
  auto stageB = [&](int buf, int kt) {
#pragma unroll
    for (int l = 0; l < 2; ++l) {
      const int i = tid + l * 512;
      const int r = i >> 3, sl = i & 7;
      GLOAD16((const char*)(Bg + (size_t)r * HH + kt * 64 + ((sl ^ (r & 7)) << 3)),
              (char*)&sm[buf][16384] + r * 128 + sl * 16);
    }
  };
  auto ldA = [&](int p, int mIdx, int s) -> bf16x8 {
    const int row = wr * 128 + mIdx * 16 + lrow;
    const int sl = (s * 4 + lkg) ^ (row & 7);
    return *(const bf16x8*)((const char*)&sm[p][0] + row * 128 + sl * 16);
  };
  auto ldB = [&](int p, int nj, int s) -> bf16x8 {
    const int row = wc * 32 + nj * 16 + lrow;
    const int sl = (s * 4 + lkg) ^ (row & 7);
    return *(const bf16x8*)((const char*)&sm[p][16384] + row * 128 + sl * 16);
  };

  f32x4 acc[8][2];
#pragma unroll
  for (int i = 0; i < 8; ++i)
#pragma unroll
    for (int j = 0; j < 2; ++j) acc[i][j] = (f32x4)(0.f);

  stageA(0, 0, 0); stageA(0, 0, 1); stageB(0, 0);

  bf16x8 af[2][2], bfr[2][2];
  const int NT = HH / 64;  // 16
  for (int t = 0; t < NT; ++t) {
    const int p = t & 1, q = p ^ 1;
    const bool pf = (t + 1 < NT);
    // ---- phase 0: mq0 (+ B read)
    if (pf) { stageA(q, t + 1, 0); WAITV2; } else { WAITV0; }
    SB0; BARRIER;
#pragma unroll
    for (int nj = 0; nj < 2; ++nj) { bfr[nj][0] = ldB(p, nj, 0); bfr[nj][1] = ldB(p, nj, 1); }
#pragma unroll
    for (int mi = 0; mi < 2; ++mi) { af[mi][0] = ldA(p, mi, 0); af[mi][1] = ldA(p, mi, 1); }
    BARRIER; WAITL0; SB0;
    __builtin_amdgcn_s_setprio(1);
#pragma unroll
    for (int mi = 0; mi < 2; ++mi)
#pragma unroll
      for (int nj = 0; nj < 2; ++nj)
#pragma unroll
        for (int s = 0; s < 2; ++s)
          acc[mi][nj] = __builtin_amdgcn_mfma_f32_16x16x32_bf16(af[mi][s], bfr[nj][s], acc[mi][nj], 0, 0, 0);
    __builtin_amdgcn_s_setprio(0); SB0; BARRIER;
    // ---- phases 1..3: mq1..mq3
#pragma unroll
    for (int mq = 1; mq < 4; ++mq) {
      if (pf) {
        if (mq == 1) stageA(q, t + 1, 1);
        else if (mq == 2) stageB(q, t + 1);
      }
#pragma unroll
      for (int mi = 0; mi < 2; ++mi) { af[mi][0] = ldA(p, mq * 2 + mi, 0); af[mi][1] = ldA(p, mq * 2 + mi, 1); }
      BARRIER; WAITL0; SB0;
      __builtin_amdgcn_s_setprio(1);
#pragma unroll
      for (int mi = 0; mi < 2; ++mi)
#pragma unroll
        for (int nj = 0; nj < 2; ++nj)
#pragma unroll
          for (int s = 0; s < 2; ++s)
            acc[mq * 2 + mi][nj] = __builtin_amdgcn_mfma_f32_16x16x32_bf16(af[mi][s], bfr[nj][s], acc[mq * 2 + mi][nj], 0, 0, 0);
      __builtin_amdgcn_s_setprio(0); SB0; BARRIER;
    }
  }

  // epilogue: LoRA + SwiGLU, bf16 store. Wave's 16 hidden cols:
  // g = it*64 + wc*16 + lrow; acc[m][0]=gate, acc[m][1]=up.
  const float4* xa4 = (const float4*)xa;
  const float4* B4 = (const float4*)Bgu;
  {
    const int g = it * 64 + wc * 16 + lrow;
    const float4 bg0 = B4[g * 2], bg1 = B4[g * 2 + 1];
    const float4 bu0 = B4[(II + g) * 2], bu1 = B4[(II + g) * 2 + 1];
#pragma unroll
    for (int m = 0; m < 8; ++m) {
      const int tb = t0 + wr * 128 + m * 16 + lkg * 4;
#pragma unroll
      for (int j = 0; j < 4; ++j) {
        const int trow = tb + j;
        const float4 xr0 = xa4[trow * 2], xr1 = xa4[trow * 2 + 1];
        const float gv = acc[m][0][j] + SCAL * (dot4(xr0, bg0) + dot4(xr1, bg1));
        const float uv = acc[m][1][j] + SCAL * (dot4(xr0, bu0) + dot4(xr1, bu1));
        const float s = gv / (1.f + __expf(-gv));
        hidden[(size_t)trow * II + g] = f2bf(uv * s);
      }
    }
  }
}

// ---------------- gemm2_8p: 256x128, BK=64, 8 waves, dbuf+swizzle ----------
__global__ __launch_bounds__(512, 1) void gemm2_8p_kernel(
    const unsigned short* __restrict__ hid, const unsigned short* __restrict__ WdnT,
    const float* __restrict__ ha, const float* __restrict__ Bdn,
    float* __restrict__ out) {
  __shared__ unsigned short sm[2][24576];  // A 256x64 @0, B 128x64 @16384; 96 KB

  const int bid = blockIdx.x;          // 8e * 4tt * 8ht
  const int e = bid >> 5, tt = (bid >> 3) & 3, ht = bid & 7;
  const int t0 = e * TT + tt * 256;
  const int h0 = ht * 128;
  const unsigned short* Ag = hid + (size_t)t0 * II;
  const unsigned short* Bg = WdnT + (size_t)e * HH * II + (size_t)h0 * II;

  const int tid = threadIdx.x;
  const int w = tid >> 6, lane = tid & 63;
  const int wr = w >> 2, wc = w & 3;
  const int lrow = lane & 15, lkg = lane >> 4;

  auto stageA = [&](int buf, int kt, int h) {
#pragma unroll
    for (int l = 0; l < 2; ++l) {
      const int i = tid + l * 512;
      const int r = i >> 3, sl = i & 7;
      const int row = h * 128 + r;
      GLOAD16((const char*)(Ag + (size_t)row * II + kt * 64 + ((sl ^ (r & 7)) << 3)),
              (char*)&sm[buf][0] + row * 128 + sl * 16);
    }
  };
  auto stageB = [&](int buf, int kt) {
#pragma unroll
    for (int l = 0; l < 2; ++l) {
      const int i = tid + l * 512;
      const int r = i >> 3, sl = i & 7;
      GLOAD16((const char*)(Bg + (size_t)r * II + kt * 64 + ((sl ^ (r & 7)) << 3)),
              (char*)&sm[buf][16384] + r * 128 + sl * 16);
    }
  };
  auto ldA = [&](int p, int mIdx, int s) -> bf16x8 {
    const int row = wr * 128 + mIdx * 16 + lrow;
    const int sl = (s * 4 + lkg) ^ (row & 7);
    return *(const bf16x8*)((const char*)&sm[p][0] + row * 128 + sl * 16);
  };
  auto ldB = [&](int p, int nj, int s) -> bf16x8 {
    const int row = wc * 32 + nj * 16 + lrow;
    const int sl = (s * 4 + lkg) ^ (row & 7);
    return *(const bf16x8*)((const char*)&sm[p][16384] + row * 128 + sl * 16);
  };

  f32x4 acc[8][2];
#pragma unroll
  for (int i = 0; i < 8; ++i)
#pragma unroll
    for (int j = 0; j < 2; ++j) acc[i][j] = (f32x4)(0.f);

  stageA(0, 0, 0); stageA(0, 0, 1); stageB(0, 0);

  bf16x8 af[2][2], bfr[2][2];
  const int NT = II / 64;  // 32
  for (int t = 0; t < NT; ++t) {
    const int p = t & 1, q = p ^ 1;
    const bool pf = (t + 1 < NT);
    // ---- phase 0: mq0 (+ B read)
    if (pf) { stageA(q, t + 1, 0); WAITV2; } else { WAITV0; }
    SB0; BARRIER;
#pragma unroll
    for (int nj = 0; nj < 2; ++nj) { bfr[nj][0] = ldB(p, nj, 0); bfr[nj][1] = ldB(p, nj, 1); }
#pragma unroll
    for (int mi = 0; mi < 2; ++mi) { af[mi][0] = ldA(p, mi, 0); af[mi][1] = ldA(p, mi, 1); }
    BARRIER; WAITL0; SB0;
    __builtin_amdgcn_s_setprio(1);
#pragma unroll
    for (int mi = 0; mi < 2; ++mi)
#pragma unroll
      for (int nj = 0; nj < 2; ++nj)
#pragma unroll
        for (int s = 0; s < 2; ++s)
          acc[mi][nj] = __builtin_amdgcn_mfma_f32_16x16x32_bf16(af[mi][s], bfr[nj][s], acc[mi][nj], 0, 0, 0);
    __builtin_amdgcn_s_setprio(0); SB0; BARRIER;
    // ---- phases 1..3: mq1..mq3
#pragma unroll
    for (int mq = 1; mq < 4; ++mq) {
      if (pf) {
        if (mq == 1) stageA(q, t + 1, 1);
        else if (mq == 2) stageB(q, t + 1);
      }
#pragma unroll
      for (int mi = 0; mi < 2; ++mi) { af[mi][0] = ldA(p, mq * 2 + mi, 0); af[mi][1] = ldA(p, mq * 2 + mi, 1); }
      BARRIER; WAITL0; SB0;
      __builtin_amdgcn_s_setprio(1);
#pragma unroll
      for (int mi = 0; mi < 2; ++mi)
#pragma unroll
        for (int nj = 0; nj < 2; ++nj)
#pragma unroll
          for (int s = 0; s < 2; ++s)
            acc[mq * 2 + mi][nj] = __builtin_amdgcn_mfma_f32_16x16x32_bf16(af[mi][s], bfr[nj][s], acc[mq * 2 + mi][nj], 0, 0, 0);
      __builtin_amdgcn_s_setprio(0); SB0; BARRIER;
    }
  }

  const float4* ha4 = (const float4*)ha;
  const float4* B4 = (const float4*)Bdn;
#pragma unroll
  for (int nj = 0; nj < 2; ++nj) {
    const int col = h0 + wc * 32 + nj * 16 + lrow;
    const float4 b0 = B4[col * 2], b1 = B4[col * 2 + 1];
#pragma unroll
    for (int m = 0; m < 8; ++m) {
      const int tb = t0 + wr * 128 + m * 16 + lkg * 4;
#pragma unroll
      for (int j = 0; j < 4; ++j) {
        const int trow = tb + j;
        const float4 hr0 = ha4[trow * 2], hr1 = ha4[trow * 2 + 1];
        out[(size_t)trow * HH + col] = acc[m][nj][j] + SCAL * (dot4(hr0, b0) + dot4(hr1, b1));
      }
    }
  }
}

// ---------------- fallback (R3): in-loop conversion GEMMs -------------------
__global__ __launch_bounds__(256) void gemm1_conv_kernel(const float* __restrict__ x,
                                                         const float* __restrict__ Wgu,
                                                         const float* __restrict__ xa,
                                                         const float* __restrict__ Bgu,
                                                         unsigned short* __restrict__ hidden) {
  __shared__ unsigned short As[128][40];
  __shared__ unsigned short Bs[128][40];
  const int bid = blockIdx.x;
  const int e = bid >> 8, rem = bid & 255, tt = rem >> 5, it = rem & 31;
  const int t0 = e * TT + tt * 128, i0 = it * 64;
  const float* Wg = Wgu + (size_t)e * HH * FF2;
  const int tid = threadIdx.x, w = tid >> 6, lane = tid & 63;
  const int wr = w >> 1, wc = w & 1, lrow = lane & 15, lk = (lane >> 4) * 8;
  f32x4 acc[4][4];
#pragma unroll
  for (int i = 0; i < 4; ++i)
#pragma unroll
    for (int j = 0; j < 4; ++j) acc[i][j] = (f32x4)(0.f);
  for (int k0 = 0; k0 < HH; k0 += 32) {
#pragma unroll
    for (int l = 0; l < 4; ++l) {
      const int idx = tid + l * 256, row = idx >> 3, kq = idx & 7;
      const float4 v = *(const float4*)(x + (size_t)(t0 + row) * HH + k0 + kq * 4);
      ushort4 p; p.x = f2bf(v.x); p.y = f2bf(v.y); p.z = f2bf(v.z); p.w = f2bf(v.w);
      *(ushort4*)&As[row][kq * 4] = p;
    }
#pragma unroll
    for (int l = 0; l < 2; ++l) {
      const int idx = tid + l * 256, col = idx & 127, kq8 = idx >> 7;
      const int gcol = i0 + (col & 63) + ((col >> 6) * II);
      union { unsigned short u[8]; uint4 v; } pk;
#pragma unroll
      for (int kk = 0; kk < 8; ++kk) pk.u[kk] = f2bf(Wg[(size_t)(k0 + kq8 * 8 + kk) * FF2 + gcol]);
      *(uint4*)&Bs[col][kq8 * 8] = pk.v;
    }
    __syncthreads();
    bf16x8 af[4], bfr[4];
#pragma unroll
    for (int mi = 0; mi < 4; ++mi) af[mi] = *(const bf16x8*)&As[wr * 64 + mi * 16 + lrow][lk];
#pragma unroll
    for (int nj = 0; nj < 4; ++nj) {
      const int c = (nj < 2) ? (wc * 32 + nj * 16) : (64 + wc * 32 + (nj - 2) * 16);
      bfr[nj] = *(const bf16x8*)&Bs[c + lrow][lk];
    }
#pragma unroll
    for (int mi = 0; mi < 4; ++mi)
#pragma unroll
      for (int nj = 0; nj < 4; ++nj)
        acc[mi][nj] = __builtin_amdgcn_mfma_f32_16x16x32_bf16(af[mi], bfr[nj], acc[mi][nj], 0, 0, 0);
    __syncthreads();
  }
  const float4* xa4 = (const float4*)xa;
  const float4* B4 = (const float4*)Bgu;
#pragma unroll
  for (int nj = 0; nj < 2; ++nj) {
    const int coln = i0 + wc * 32 + nj * 16 + lrow;
    const float4 bg0 = B4[coln * 2], bg1 = B4[coln * 2 + 1];
    const float4 bu0 = B4[(II + coln) * 2], bu1 = B4[(II + coln) * 2 + 1];
#pragma unroll
    for (int mi = 0; mi < 4; ++mi) {
      const int tb = t0 + wr * 64 + mi * 16 + (lane >> 4) * 4;
#pragma unroll
      for (int j = 0; j < 4; ++j) {
        const int t = tb + j;
        const float4 xr0 = xa4[t * 2], xr1 = xa4[t * 2 + 1];
        const float g = acc[mi][nj][j] + SCAL * (dot4(xr0, bg0) + dot4(xr1, bg1));
        const float u = acc[mi][nj + 2][j] + SCAL * (dot4(xr0, bu0) + dot4(xr1, bu1));
        const float s = g / (1.f + __expf(-g));
        hidden[(size_t)t * II + coln] = f2bf(u * s);
      }
    }
  }
}

__global__ __launch_bounds__(256) void gemm2_conv_kernel(const unsigned short* __restrict__ hid,
                                                         const float* __restrict__ Wdn,
                                                         const float* __restrict__ ha,
                                                         const float* __restrict__ Bdn,
                                                         float* __restrict__ out) {
  __shared__ unsigned short As[128][40];
  __shared__ unsigned short Bs[128][40];
  const int bid = blockIdx.x;
  const int e = bid >> 6, rem = bid & 63, tt = rem >> 3, ht = rem & 7;
  const int t0 = e * TT + tt * 128, h0 = ht * 128;
  const float* Wd = Wdn + (size_t)e * II * HH;
  const int tid = threadIdx.x, w = tid >> 6, lane = tid & 63;
  const int wr = w >> 1, wc = w & 1, lrow = lane & 15, lk = (lane >> 4) * 8;
  f32x4 acc[4][4];
#pragma unroll
  for (int i = 0; i < 4; ++i)
#pragma unroll
    for (int j = 0; j < 4; ++j) acc[i][j] = (f32x4)(0.f);
  for (int k0 = 0; k0 < II; k0 += 32) {
#pragma unroll
    for (int l = 0; l < 2; ++l) {
      const int idx = tid + l * 256, row = idx >> 2, kq8 = idx & 3;
      *(uint4*)&As[row][kq8 * 8] = *(const uint4*)(hid + (size_t)(t0 + row) * II + k0 + kq8 * 8);
    }
#pragma unroll
    for (int l = 0; l < 2; ++l) {
      const int idx = tid + l * 256, col = idx & 127, kq8 = idx >> 7;
      union { unsigned short u[8]; uint4 v; } pk;
#pragma unroll
      for (int kk = 0; kk < 8; ++kk) pk.u[kk] = f2bf(Wd[(size_t)(k0 + kq8 * 8 + kk) * HH + h0 + col]);
      *(uint4*)&Bs[col][kq8 * 8] = pk.v;
    }
    __syncthreads();
    bf16x8 af[4], bfr[4];
#pragma unroll
    for (int mi = 0; mi < 4; ++mi) af[mi] = *(const bf16x8*)&As[wr * 64 + mi * 16 + lrow][lk];
#pragma unroll
    for (int nj = 0; nj < 4; ++nj) bfr[nj] = *(const bf16x8*)&Bs[wc * 64 + nj * 16 + lrow][lk];
#pragma unroll
    for (int mi = 0; mi < 4; ++mi)
#pragma unroll
      for (int nj = 0; nj < 4; ++nj)
        acc[mi][nj] = __builtin_amdgcn_mfma_f32_16x16x32_bf16(af[mi], bfr[nj], acc[mi][nj], 0, 0, 0);
    __syncthreads();
  }
  const float4* ha4 = (const float4*)ha;
  const float4* B4 = (const float4*)Bdn;
#pragma unroll
  for (int nj = 0; nj < 4; ++nj) {
    const int coln = h0 + wc * 64 + nj * 16 + lrow;
    const float4 b0 = B4[coln * 2], b1 = B4[coln * 2 + 1];
#pragma unroll
    for (int mi = 0; mi < 4; ++mi) {
      const int tb = t0 + wr * 64 + mi * 16 + (lane >> 4) * 4;
#pragma unroll
      for (int j = 0; j < 4; ++j) {
        const int t = tb + j;
        const float4 hr0 = ha4[t * 2], hr1 = ha4[t * 2 + 1];
        out[(size_t)t * HH + coln] = acc[mi][nj][j] + SCAL * (dot4(hr0, b0) + dot4(hr1, b1));
      }
    }
  }
}

extern "C" void kernel_launch(void* const* d_in, const int* in_sizes, int n_in,
                              void* d_out, int out_size, void* d_ws, size_t ws_size,
                              hipStream_t stream) {
  const float* x   = (const float*)d_in[0];
  const float* Wgu = (const float*)d_in[1];
  const float* Wdn = (const float*)d_in[2];
  const float* Agu = (const float*)d_in[3];
  const float* Bgu = (const float*)d_in[4];
  const float* Adn = (const float*)d_in[5];
  const float* Bdn = (const float*)d_in[6];
  float* out = (float*)d_out;

  char* ws = (char*)d_ws;
  unsigned short* hidden = (unsigned short*)ws;                      //  32 MB
  const size_t OFF_XB  = (size_t)NROW * II * 2;                      //  32 MB
  const size_t OFF_WGU = OFF_XB + (size_t)NROW * HH * 2;             //  48 MB
  const size_t OFF_WDN = OFF_WGU + (size_t)NE * FF2 * HH * 2;        // 112 MB
  const size_t OFF_XA  = OFF_WDN + (size_t)NE * HH * II * 2;         // 144 MB
  const size_t OFF_HA  = OFF_XA + (size_t)NROW * RR * 4;
  const size_t NEED    = OFF_HA + (size_t)NROW * RR * 4;

  if (ws_size >= NEED) {
    unsigned short* xb   = (unsigned short*)(ws + OFF_XB);
    unsigned short* WguT = (unsigned short*)(ws + OFF_WGU);
    unsigned short* WdnT = (unsigned short*)(ws + OFF_WDN);
    float* xa = (float*)(ws + OFF_XA);
    float* ha = (float*)(ws + OFF_HA);

    convx_kernel<<<(NROW * HH) / (256 * 8), 256, 0, stream>>>(x, xb);
    transconv_gu_kernel<<<NE * 16 * 64, 256, 0, stream>>>(Wgu, WguT);
    transconv_dn_kernel<<<NE * 32 * 16, 256, 0, stream>>>(Wdn, WdnT);
    rowdot_kernel<HH><<<NROW / 4, 256, 0, stream>>>(x, Agu, xa);
    gemm1_8p_kernel<<<NE * 4 * 32, 512, 0, stream>>>(xb, WguT, xa, Bgu, hidden);
    rowdot_bf16_kernel<<<NROW / 4, 256, 0, stream>>>(hidden, Adn, ha);
    gemm2_8p_kernel<<<NE * 4 * 8, 512, 0, stream>>>(hidden, WdnT, ha, Bdn, out);
  } else {
    float* xa = (float*)(ws + OFF_XB);
    float* ha = xa + (size_t)NROW * RR;
    rowdot_kernel<HH><<<NROW / 4, 256, 0, stream>>>(x, Agu, xa);
    gemm1_conv_kernel<<<NE * 8 * 32, 256, 0, stream>>>(x, Wgu, xa, Bgu, hidden);
    rowdot_bf16_kernel<<<NROW / 4, 256, 0, stream>>>(hidden, Adn, ha);
    gemm2_conv_kernel<<<NE * 8 * 8, 256, 0, stream>>>(hidden, Wdn, ha, Bdn, out);
  }
}

// Round 10
// 389.269 us; speedup vs baseline: 1.5329x; 1.0257x over previous
//
#include <hip/hip_runtime.h>
#include <math.h>

// Llama4 experts + shared LoRA (rank 8) — bf16 MFMA, 8-phase pipelined GEMMs.
// E=8, T=1024, H=1024, I=2048, F2=4096, R=8, scaling=2.
//
// R9->R10: ONLY change = XCD-colocate block swizzle on both 8p GEMMs.
// Default round-robin puts the 8 blocks sharing an A panel on 8 different
// XCDs -> zero L2 reuse (R9 gemm2: 437 MB HBM/dispatch = exact no-reuse
// prediction, 170us memory-bound). New map: XCD = bid%8 = expert; per-XCD
// sequence groups co-resident blocks into L2-sized working sets
// (gemm1: {4tt x 8it} = 4MB; gemm2: whole expert = 8MB).
//
// 8-phase K-loop per K-tile (BK=64), counted vmcnt(2), raw s_barrier,
// setprio around MFMA, XOR slot-swizzle (pre-swizzled global source +
// swizzled ds_read, linear LDS dest).

#define NE 8
#define TT 1024
#define HH 1024
#define II 2048
#define FF2 4096
#define RR 8
#define NROW (NE * TT)
#define SCAL 2.0f

typedef __bf16 bf16x8 __attribute__((ext_vector_type(8)));
typedef float f32x4 __attribute__((ext_vector_type(4)));

#define GLOAD16(g, l)                                                        \
  __builtin_amdgcn_global_load_lds((const __attribute__((address_space(1))) void*)(g), \
                                   (__attribute__((address_space(3))) void*)(l), 16, 0, 0)
#define BARRIER __builtin_amdgcn_s_barrier()
#define SB0 __builtin_amdgcn_sched_barrier(0)
#define WAITV2 asm volatile("s_waitcnt vmcnt(2)" ::: "memory")
#define WAITV0 asm volatile("s_waitcnt vmcnt(0)" ::: "memory")
#define WAITL0 asm volatile("s_waitcnt lgkmcnt(0)" ::: "memory")

__device__ __forceinline__ unsigned short f2bf(float f) {
  unsigned int u = __float_as_uint(f);
  u += 0x7fffu + ((u >> 16) & 1u);  // RNE
  return (unsigned short)(u >> 16);
}
__device__ __forceinline__ float dot4(float4 a, float4 b) {
  return a.x * b.x + a.y * b.y + a.z * b.z + a.w * b.w;
}

// ---------------- conversion pre-passes -------------------------------------
__global__ __launch_bounds__(256) void convx_kernel(const float* __restrict__ x,
                                                    unsigned short* __restrict__ xb) {
  const int i = blockIdx.x * 256 + threadIdx.x;
  const float4 a = *(const float4*)(x + (size_t)i * 8);
  const float4 b = *(const float4*)(x + (size_t)i * 8 + 4);
  union { unsigned short u[8]; uint4 v; } pk;
  pk.u[0] = f2bf(a.x); pk.u[1] = f2bf(a.y); pk.u[2] = f2bf(a.z); pk.u[3] = f2bf(a.w);
  pk.u[4] = f2bf(b.x); pk.u[5] = f2bf(b.y); pk.u[6] = f2bf(b.z); pk.u[7] = f2bf(b.w);
  *(uint4*)(xb + (size_t)i * 8) = pk.v;
}

// Wgu [e][1024][4096] f32 -> WguT [e][4096][1024] bf16, 16-granular interleave:
// gate col gc -> row (gc>>4)*32 + (gc&15); up col uc -> row (uc>>4)*32+16+(uc&15).
__global__ __launch_bounds__(256) void transconv_gu_kernel(const float* __restrict__ W,
                                                           unsigned short* __restrict__ WT) {
  __shared__ float ts[64][65];
  const int bid = blockIdx.x;           // 8*16*64
  const int nt = bid & 63, kt = (bid >> 6) & 15, e = bid >> 10;
  const float* Win = W + (size_t)e * HH * FF2 + (size_t)(kt * 64) * FF2 + nt * 64;
  const int tid = threadIdx.x;
#pragma unroll
  for (int l = 0; l < 4; ++l) {
    const int idx = tid + l * 256, r = idx >> 4, c4 = idx & 15;
    const float4 v = *(const float4*)(Win + (size_t)r * FF2 + c4 * 4);
    ts[r][c4 * 4 + 0] = v.x; ts[r][c4 * 4 + 1] = v.y;
    ts[r][c4 * 4 + 2] = v.z; ts[r][c4 * 4 + 3] = v.w;
  }
  __syncthreads();
  unsigned short* We = WT + (size_t)e * FF2 * HH;
#pragma unroll
  for (int l = 0; l < 2; ++l) {
    const int idx = tid + l * 256, j = idx >> 3, q = idx & 7;
    int orow;
    if (nt < 32) orow = (nt * 4 + (j >> 4)) * 32 + (j & 15);             // gate
    else         orow = ((nt - 32) * 4 + (j >> 4)) * 32 + 16 + (j & 15); // up
    union { unsigned short u[8]; uint4 v; } pk;
#pragma unroll
    for (int kk = 0; kk < 8; ++kk) pk.u[kk] = f2bf(ts[q * 8 + kk][j]);
    *(uint4*)(We + (size_t)orow * HH + kt * 64 + q * 8) = pk.v;
  }
}

// Wdn [e][2048][1024] f32 -> WdnT [e][1024][2048] bf16 (plain transpose).
__global__ __launch_bounds__(256) void transconv_dn_kernel(const float* __restrict__ W,
                                                           unsigned short* __restrict__ WT) {
  __shared__ float ts[64][65];
  const int bid = blockIdx.x;           // 8*32*16
  const int nt = bid & 15, kt = (bid >> 4) & 31, e = bid >> 9;
  const float* Win = W + (size_t)e * II * HH + (size_t)(kt * 64) * HH + nt * 64;
  const int tid = threadIdx.x;
#pragma unroll
  for (int l = 0; l < 4; ++l) {
    const int idx = tid + l * 256, r = idx >> 4, c4 = idx & 15;
    const float4 v = *(const float4*)(Win + (size_t)r * HH + c4 * 4);
    ts[r][c4 * 4 + 0] = v.x; ts[r][c4 * 4 + 1] = v.y;
    ts[r][c4 * 4 + 2] = v.z; ts[r][c4 * 4 + 3] = v.w;
  }
  __syncthreads();
  unsigned short* Wout = WT + (size_t)e * HH * II + (size_t)(nt * 64) * II + kt * 64;
#pragma unroll
  for (int l = 0; l < 2; ++l) {
    const int idx = tid + l * 256, j = idx >> 3, q = idx & 7;
    union { unsigned short u[8]; uint4 v; } pk;
#pragma unroll
    for (int kk = 0; kk < 8; ++kk) pk.u[kk] = f2bf(ts[q * 8 + kk][j]);
    *(uint4*)(Wout + (size_t)j * II + q * 8) = pk.v;
  }
}

// ---------------- rank-8 row dots -------------------------------------------
template <int K>
__global__ __launch_bounds__(256) void rowdot_kernel(const float* __restrict__ x,
                                                     const float* __restrict__ A,
                                                     float* __restrict__ xa) {
  const int w = threadIdx.x >> 6, lane = threadIdx.x & 63;
  const int t = blockIdx.x * 4 + w;
  const float* xrow = x + (size_t)t * K;
  float acc[RR];
#pragma unroll
  for (int r = 0; r < RR; ++r) acc[r] = 0.f;
#pragma unroll
  for (int c = 0; c < K / 256; ++c) {
    const float4 xv = *(const float4*)(xrow + c * 256 + lane * 4);
#pragma unroll
    for (int r = 0; r < RR; ++r) {
      const float4 av = *(const float4*)(A + (size_t)r * K + c * 256 + lane * 4);
      acc[r] += dot4(xv, av);
    }
  }
#pragma unroll
  for (int r = 0; r < RR; ++r) {
    float v = acc[r];
#pragma unroll
    for (int off = 32; off > 0; off >>= 1) v += __shfl_down(v, off, 64);
    if (lane == 0) xa[(size_t)t * RR + r] = v;
  }
}

__global__ __launch_bounds__(256) void rowdot_bf16_kernel(const unsigned short* __restrict__ h,
                                                          const float* __restrict__ A,
                                                          float* __restrict__ ha) {
  const int w = threadIdx.x >> 6, lane = threadIdx.x & 63;
  const int t = blockIdx.x * 4 + w;
  const unsigned short* hrow = h + (size_t)t * II;
  float acc[RR];
#pragma unroll
  for (int r = 0; r < RR; ++r) acc[r] = 0.f;
#pragma unroll
  for (int c = 0; c < II / 512; ++c) {
    const uint4 v = *(const uint4*)(hrow + c * 512 + lane * 8);
    float xv[8];
    xv[0] = __uint_as_float(v.x << 16); xv[1] = __uint_as_float(v.x & 0xffff0000u);
    xv[2] = __uint_as_float(v.y << 16); xv[3] = __uint_as_float(v.y & 0xffff0000u);
    xv[4] = __uint_as_float(v.z << 16); xv[5] = __uint_as_float(v.z & 0xffff0000u);
    xv[6] = __uint_as_float(v.w << 16); xv[7] = __uint_as_float(v.w & 0xffff0000u);
#pragma unroll
    for (int r = 0; r < RR; ++r) {
      const float4 a0 = *(const float4*)(A + (size_t)r * II + c * 512 + lane * 8);
      const float4 a1 = *(const float4*)(A + (size_t)r * II + c * 512 + lane * 8 + 4);
      acc[r] += xv[0] * a0.x + xv[1] * a0.y + xv[2] * a0.z + xv[3] * a0.w +
                xv[4] * a1.x + xv[5] * a1.y + xv[6] * a1.z + xv[7] * a1.w;
    }
  }
#pragma unroll
  for (int r = 0; r < RR; ++r) {
    float v = acc[r];
#pragma unroll
    for (int off = 32; off > 0; off >>= 1) v += __shfl_down(v, off, 64);
    if (lane == 0) ha[(size_t)t * RR + r] = v;
  }
}

// ---------------- gemm1_8p: 256x128, BK=64, 8 waves (2Mx4N), dbuf+swizzle ---
// XCD swizzle: e = bid&7 (XCD), s = bid>>3; g = s>>5 (it-octet), w = s&31:
// tt = w>>3, it = g*8 + (w&7). Co-resident 32 blocks/XCD share 4 A panels
// (2 MB, 8x reuse) + 8 B panels (2 MB, 4x reuse) = 4 MB = L2.
__global__ __launch_bounds__(512, 1) void gemm1_8p_kernel(
    const unsigned short* __restrict__ xb, const unsigned short* __restrict__ WguT,
    const float* __restrict__ xa, const float* __restrict__ Bgu,
    unsigned short* __restrict__ hidden) {
  __shared__ unsigned short sm[2][24576];  // A 256x64 @0, B 128x64 @16384; 96 KB

  const int bid = blockIdx.x;          // 1024 = 8e * 4tt * 32it (swizzled)
  const int e = bid & 7;
  const int s = bid >> 3;
  const int g = s >> 5, wq = s & 31;
  const int tt = wq >> 3, it = (g << 3) | (wq & 7);
  const int t0 = e * TT + tt * 256;
  const unsigned short* Ag = xb + (size_t)t0 * HH;
  const unsigned short* Bg = WguT + (size_t)e * FF2 * HH + (size_t)(it * 128) * HH;

  const int tid = threadIdx.x;
  const int w = tid >> 6, lane = tid & 63;
  const int wr = w >> 2, wc = w & 3;
  const int lrow = lane & 15, lkg = lane >> 4;

  auto stageA = [&](int buf, int kt, int h) {
#pragma unroll
    for (int l = 0; l < 2; ++l) {
      const int i = tid + l * 512;
      const int r = i >> 3, sl = i & 7;
      const int row = h * 128 + r;
      GLOAD16((const char*)(Ag + (size_t)row * HH + kt * 64 + ((sl ^ (r & 7)) << 3)),
              (char*)&sm[buf][0] + row * 128 + sl * 16);
    }
  };
  auto stageB = [&](int buf, int kt) {
#pragma unroll
    for (int l = 0; l < 2; ++l) {
      const int i = tid + l * 512;
      const int r = i >> 3, sl = i & 7;
      GLOAD16((const char*)(Bg + (size_t)r * HH + kt * 64 + ((sl ^ (r & 7)) << 3)),
              (char*)&sm[buf][16384] + r * 128 + sl * 16);
    }
  };
  auto ldA = [&](int p, int mIdx, int s2) -> bf16x8 {
    const int row = wr * 128 + mIdx * 16 + lrow;
    const int sl = (s2 * 4 + lkg) ^ (row & 7);
    return *(const bf16x8*)((const char*)&sm[p][0] + row * 128 + sl * 16);
  };
  auto ldB = [&](int p, int nj, int s2) -> bf16x8 {
    const int row = wc * 32 + nj * 16 + lrow;
    const int sl = (s2 * 4 + lkg) ^ (row & 7);
    return *(const bf16x8*)((const char*)&sm[p][16384] + row * 128 + sl * 16);
  };

  f32x4 acc[8][2];
#pragma unroll
  for (int i = 0; i < 8; ++i)
#pragma unroll
    for (int j = 0; j < 2; ++j) acc[i][j] = (f32x4)(0.f);

  stageA(0, 0, 0); stageA(0, 0, 1); stageB(0, 0);

  bf16x8 af[2][2], bfr[2][2];
  const int NT = HH / 64;  // 16
  for (int t = 0; t < NT; ++t) {
    const int p = t & 1, q = p ^ 1;
    const bool pf = (t + 1 < NT);
    // ---- phase 0: mq0 (+ B read)
    if (pf) { stageA(q, t + 1, 0); WAITV2; } else { WAITV0; }
    SB0; BARRIER;
#pragma unroll
    for (int nj = 0; nj < 2; ++nj) { bfr[nj][0] = ldB(p, nj, 0); bfr[nj][1] = ldB(p, nj, 1); }
#pragma unroll
    for (int mi = 0; mi < 2; ++mi) { af[mi][0] = ldA(p, mi, 0); af[mi][1] = ldA(p, mi, 1); }
    BARRIER; WAITL0; SB0;
    __builtin_amdgcn_s_setprio(1);
#pragma unroll
    for (int mi = 0; mi < 2; ++mi)
#pragma unroll
      for (int nj = 0; nj < 2; ++nj)
#pragma unroll
        for (int s2 = 0; s2 < 2; ++s2)
          acc[mi][nj] = __builtin_amdgcn_mfma_f32_16x16x32_bf16(af[mi][s2], bfr[nj][s2], acc[mi][nj], 0, 0, 0);
    __builtin_amdgcn_s_setprio(0); SB0; BARRIER;
    // ---- phases 1..3: mq1..mq3
#pragma unroll
    for (int mq = 1; mq < 4; ++mq) {
      if (pf) {
        if (mq == 1) stageA(q, t + 1, 1);
        else if (mq == 2) stageB(q, t + 1);
      }
#pragma unroll
      for (int mi = 0; mi < 2; ++mi) { af[mi][0] = ldA(p, mq * 2 + mi, 0); af[mi][1] = ldA(p, mq * 2 + mi, 1); }
      BARRIER; WAITL0; SB0;
      __builtin_amdgcn_s_setprio(1);
#pragma unroll
      for (int mi = 0; mi < 2; ++mi)
#pragma unroll
        for (int nj = 0; nj < 2; ++nj)
#pragma unroll
          for (int s2 = 0; s2 < 2; ++s2)
            acc[mq * 2 + mi][nj] = __builtin_amdgcn_mfma_f32_16x16x32_bf16(af[mi][s2], bfr[nj][s2], acc[mq * 2 + mi][nj], 0, 0, 0);
      __builtin_amdgcn_s_setprio(0); SB0; BARRIER;
    }
  }

  // epilogue: LoRA + SwiGLU, bf16 store. Wave's 16 hidden cols:
  // g = it*64 + wc*16 + lrow; acc[m][0]=gate, acc[m][1]=up.
  const float4* xa4 = (const float4*)xa;
  const float4* B4 = (const float4*)Bgu;
  {
    const int gc = it * 64 + wc * 16 + lrow;
    const float4 bg0 = B4[gc * 2], bg1 = B4[gc * 2 + 1];
    const float4 bu0 = B4[(II + gc) * 2], bu1 = B4[(II + gc) * 2 + 1];
#pragma unroll
    for (int m = 0; m < 8; ++m) {
      const int tb = t0 + wr * 128 + m * 16 + lkg * 4;
#pragma unroll
      for (int j = 0; j < 4; ++j) {
        const int trow = tb + j;
        const float4 xr0 = xa4[trow * 2], xr1 = xa4[trow * 2 + 1];
        const float gv = acc[m][0][j] + SCAL * (dot4(xr0, bg0) + dot4(xr1, bg1));
        const float uv = acc[m][1][j] + SCAL * (dot4(xr0, bu0) + dot4(xr1, bu1));
        const float sg = gv / (1.f + __expf(-gv));
        hidden[(size_t)trow * II + gc] = f2bf(uv * sg);
      }
    }
  }
}

// ---------------- gemm2_8p: 256x128, BK=64, 8 waves, dbuf+swizzle ----------
// XCD swizzle: e = bid&7 (XCD), s = bid>>3: tt = s>>3, ht = s&7. All 32
// blocks of expert e co-resident on XCD e (hidden_e 4MB + WdnT_e 4MB).
__global__ __launch_bounds__(512, 1) void gemm2_8p_kernel(
    const unsigned short* __restrict__ hid, const unsigned short* __restrict__ WdnT,
    const float* __restrict__ ha, const float* __restrict__ Bdn,
    float* __restrict__ out) {
  __shared__ unsigned short sm[2][24576];  // A 256x64 @0, B 128x64 @16384; 96 KB

  const int bid = blockIdx.x;          // 256 = 8e * 4tt * 8ht (swizzled)
  const int e = bid & 7;
  const int s = bid >> 3;
  const int tt = s >> 3, ht = s & 7;
  const int t0 = e * TT + tt * 256;
  const int h0 = ht * 128;
  const unsigned short* Ag = hid + (size_t)t0 * II;
  const unsigned short* Bg = WdnT + (size_t)e * HH * II + (size_t)h0 * II;

  const int tid = threadIdx.x;
  const int w = tid >> 6, lane = tid & 63;
  const int wr = w >> 2, wc = w & 3;
  const int lrow = lane & 15, lkg = lane >> 4;

  auto stageA = [&](int buf, int kt, int h) {
#pragma unroll
    for (int l = 0; l < 2; ++l) {
      const int i = tid + l * 512;
      const int r = i >> 3, sl = i & 7;
      const int row = h * 128 + r;
      GLOAD16((const char*)(Ag + (size_t)row * II + kt * 64 + ((sl ^ (r & 7)) << 3)),
              (char*)&sm[buf][0] + row * 128 + sl * 16);
    }
  };
  auto stageB = [&](int buf, int kt) {
#pragma unroll
    for (int l = 0; l < 2; ++l) {
      const int i = tid + l * 512;
      const int r = i >> 3, sl = i & 7;
      GLOAD16((const char*)(Bg + (size_t)r * II + kt * 64 + ((sl ^ (r & 7)) << 3)),
              (char*)&sm[buf][16384] + r * 128 + sl * 16);
    }
  };
  auto ldA = [&](int p, int mIdx, int s2) -> bf16x8 {
    const int row = wr * 128 + mIdx * 16 + lrow;
    const int sl = (s2 * 4 + lkg) ^ (row & 7);
    return *(const bf16x8*)((const char*)&sm[p][0] + row * 128 + sl * 16);
  };
  auto ldB = [&](int p, int nj, int s2) -> bf16x8 {
    const int row = wc * 32 + nj * 16 + lrow;
    const int sl = (s2 * 4 + lkg) ^ (row & 7);
    return *(const bf16x8*)((const char*)&sm[p][16384] + row * 128 + sl * 16);
  };

  f32x4 acc[8][2];
#pragma unroll
  for (int i = 0; i < 8; ++i)
#pragma unroll
    for (int j = 0; j < 2; ++j) acc[i][j] = (f32x4)(0.f);

  stageA(0, 0, 0); stageA(0, 0, 1); stageB(0, 0);

  bf16x8 af[2][2], bfr[2][2];
  const int NT = II / 64;  // 32
  for (int t = 0; t < NT; ++t) {
    const int p = t & 1, q = p ^ 1;
    const bool pf = (t + 1 < NT);
    // ---- phase 0: mq0 (+ B read)
    if (pf) { stageA(q, t + 1, 0); WAITV2; } else { WAITV0; }
    SB0; BARRIER;
#pragma unroll
    for (int nj = 0; nj < 2; ++nj) { bfr[nj][0] = ldB(p, nj, 0); bfr[nj][1] = ldB(p, nj, 1); }
#pragma unroll
    for (int mi = 0; mi < 2; ++mi) { af[mi][0] = ldA(p, mi, 0); af[mi][1] = ldA(p, mi, 1); }
    BARRIER; WAITL0; SB0;
    __builtin_amdgcn_s_setprio(1);
#pragma unroll
    for (int mi = 0; mi < 2; ++mi)
#pragma unroll
      for (int nj = 0; nj < 2; ++nj)
#pragma unroll
        for (int s2 = 0; s2 < 2; ++s2)
          acc[mi][nj] = __builtin_amdgcn_mfma_f32_16x16x32_bf16(af[mi][s2], bfr[nj][s2], acc[mi][nj], 0, 0, 0);
    __builtin_amdgcn_s_setprio(0); SB0; BARRIER;
    // ---- phases 1..3: mq1..mq3
#pragma unroll
    for (int mq = 1; mq < 4; ++mq) {
      if (pf) {
        if (mq == 1) stageA(q, t + 1, 1);
        else if (mq == 2) stageB(q, t + 1);
      }
#pragma unroll
      for (int mi = 0; mi < 2; ++mi) { af[mi][0] = ldA(p, mq * 2 + mi, 0); af[mi][1] = ldA(p, mq * 2 + mi, 1); }
      BARRIER; WAITL0; SB0;
      __builtin_amdgcn_s_setprio(1);
#pragma unroll
      for (int mi = 0; mi < 2; ++mi)
#pragma unroll
        for (int nj = 0; nj < 2; ++nj)
#pragma unroll
          for (int s2 = 0; s2 < 2; ++s2)
            acc[mq * 2 + mi][nj] = __builtin_amdgcn_mfma_f32_16x16x32_bf16(af[mi][s2], bfr[nj][s2], acc[mq * 2 + mi][nj], 0, 0, 0);
      __builtin_amdgcn_s_setprio(0); SB0; BARRIER;
    }
  }

  const float4* ha4 = (const float4*)ha;
  const float4* B4 = (const float4*)Bdn;
#pragma unroll
  for (int nj = 0; nj < 2; ++nj) {
    const int col = h0 + wc * 32 + nj * 16 + lrow;
    const float4 b0 = B4[col * 2], b1 = B4[col * 2 + 1];
#pragma unroll
    for (int m = 0; m < 8; ++m) {
      const int tb = t0 + wr * 128 + m * 16 + lkg * 4;
#pragma unroll
      for (int j = 0; j < 4; ++j) {
        const int trow = tb + j;
        const float4 hr0 = ha4[trow * 2], hr1 = ha4[trow * 2 + 1];
        out[(size_t)trow * HH + col] = acc[m][nj][j] + SCAL * (dot4(hr0, b0) + dot4(hr1, b1));
      }
    }
  }
}

// ---------------- fallback (R3): in-loop conversion GEMMs -------------------
__global__ __launch_bounds__(256) void gemm1_conv_kernel(const float* __restrict__ x,
                                                         const float* __restrict__ Wgu,
                                                         const float* __restrict__ xa,
                                                         const float* __restrict__ Bgu,
                                                         unsigned short* __restrict__ hidden) {
  __shared__ unsigned short As[128][40];
  __shared__ unsigned short Bs[128][40];
  const int bid = blockIdx.x;
  const int e = bid >> 8, rem = bid & 255, tt = rem >> 5, it = rem & 31;
  const int t0 = e * TT + tt * 128, i0 = it * 64;
  const float* Wg = Wgu + (size_t)e * HH * FF2;
  const int tid = threadIdx.x, w = tid >> 6, lane = tid & 63;
  const int wr = w >> 1, wc = w & 1, lrow = lane & 15, lk = (lane >> 4) * 8;
  f32x4 acc[4][4];
#pragma unroll
  for (int i = 0; i < 4; ++i)
#pragma unroll
    for (int j = 0; j < 4; ++j) acc[i][j] = (f32x4)(0.f);
  for (int k0 = 0; k0 < HH; k0 += 32) {
#pragma unroll
    for (int l = 0; l < 4; ++l) {
      const int idx = tid + l * 256, row = idx >> 3, kq = idx & 7;
      const float4 v = *(const float4*)(x + (size_t)(t0 + row) * HH + k0 + kq * 4);
      ushort4 p; p.x = f2bf(v.x); p.y = f2bf(v.y); p.z = f2bf(v.z); p.w = f2bf(v.w);
      *(ushort4*)&As[row][kq * 4] = p;
    }
#pragma unroll
    for (int l = 0; l < 2; ++l) {
      const int idx = tid + l * 256, col = idx & 127, kq8 = idx >> 7;
      const int gcol = i0 + (col & 63) + ((col >> 6) * II);
      union { unsigned short u[8]; uint4 v; } pk;
#pragma unroll
      for (int kk = 0; kk < 8; ++kk) pk.u[kk] = f2bf(Wg[(size_t)(k0 + kq8 * 8 + kk) * FF2 + gcol]);
      *(uint4*)&Bs[col][kq8 * 8] = pk.v;
    }
    __syncthreads();
    bf16x8 af[4], bfr[4];
#pragma unroll
    for (int mi = 0; mi < 4; ++mi) af[mi] = *(const bf16x8*)&As[wr * 64 + mi * 16 + lrow][lk];
#pragma unroll
    for (int nj = 0; nj < 4; ++nj) {
      const int c = (nj < 2) ? (wc * 32 + nj * 16) : (64 + wc * 32 + (nj - 2) * 16);
      bfr[nj] = *(const bf16x8*)&Bs[c + lrow][lk];
    }
#pragma unroll
    for (int mi = 0; mi < 4; ++mi)
#pragma unroll
      for (int nj = 0; nj < 4; ++nj)
        acc[mi][nj] = __builtin_amdgcn_mfma_f32_16x16x32_bf16(af[mi], bfr[nj], acc[mi][nj], 0, 0, 0);
    __syncthreads();
  }
  const float4* xa4 = (const float4*)xa;
  const float4* B4 = (const float4*)Bgu;
#pragma unroll
  for (int nj = 0; nj < 2; ++nj) {
    const int coln = i0 + wc * 32 + nj * 16 + lrow;
    const float4 bg0 = B4[coln * 2], bg1 = B4[coln * 2 + 1];
    const float4 bu0 = B4[(II + coln) * 2], bu1 = B4[(II + coln) * 2 + 1];
#pragma unroll
    for (int mi = 0; mi < 4; ++mi) {
      const int tb = t0 + wr * 64 + mi * 16 + (lane >> 4) * 4;
#pragma unroll
      for (int j = 0; j < 4; ++j) {
        const int t = tb + j;
        const float4 xr0 = xa4[t * 2], xr1 = xa4[t * 2 + 1];
        const float g = acc[mi][nj][j] + SCAL * (dot4(xr0, bg0) + dot4(xr1, bg1));
        const float u = acc[mi][nj + 2][j] + SCAL * (dot4(xr0, bu0) + dot4(xr1, bu1));
        const float s = g / (1.f + __expf(-g));
        hidden[(size_t)t * II + coln] = f2bf(u * s);
      }
    }
  }
}

__global__ __launch_bounds__(256) void gemm2_conv_kernel(const unsigned short* __restrict__ hid,
                                                         const float* __restrict__ Wdn,
                                                         const float* __restrict__ ha,
                                                         const float* __restrict__ Bdn,
                                                         float* __restrict__ out) {
  __shared__ unsigned short As[128][40];
  __shared__ unsigned short Bs[128][40];
  const int bid = blockIdx.x;
  const int e = bid >> 6, rem = bid & 63, tt = rem >> 3, ht = rem & 7;
  const int t0 = e * TT + tt * 128, h0 = ht * 128;
  const float* Wd = Wdn + (size_t)e * II * HH;
  const int tid = threadIdx.x, w = tid >> 6, lane = tid & 63;
  const int wr = w >> 1, wc = w & 1, lrow = lane & 15, lk = (lane >> 4) * 8;
  f32x4 acc[4][4];
#pragma unroll
  for (int i = 0; i < 4; ++i)
#pragma unroll
    for (int j = 0; j < 4; ++j) acc[i][j] = (f32x4)(0.f);
  for (int k0 = 0; k0 < II; k0 += 32) {
#pragma unroll
    for (int l = 0; l < 2; ++l) {
      const int idx = tid + l * 256, row = idx >> 2, kq8 = idx & 3;
      *(uint4*)&As[row][kq8 * 8] = *(const uint4*)(hid + (size_t)(t0 + row) * II + k0 + kq8 * 8);
    }
#pragma unroll
    for (int l = 0; l < 2; ++l) {
      const int idx = tid + l * 256, col = idx & 127, kq8 = idx >> 7;
      union { unsigned short u[8]; uint4 v; } pk;
#pragma unroll
      for (int kk = 0; kk < 8; ++kk) pk.u[kk] = f2bf(Wd[(size_t)(k0 + kq8 * 8 + kk) * HH + h0 + col]);
      *(uint4*)&Bs[col][kq8 * 8] = pk.v;
    }
    __syncthreads();
    bf16x8 af[4], bfr[4];
#pragma unroll
    for (int mi = 0; mi < 4; ++mi) af[mi] = *(const bf16x8*)&As[wr * 64 + mi * 16 + lrow][lk];
#pragma unroll
    for (int nj = 0; nj < 4; ++nj) bfr[nj] = *(const bf16x8*)&Bs[wc * 64 + nj * 16 + lrow][lk];
#pragma unroll
    for (int mi = 0; mi < 4; ++mi)
#pragma unroll
      for (int nj = 0; nj < 4; ++nj)
        acc[mi][nj] = __builtin_amdgcn_mfma_f32_16x16x32_bf16(af[mi], bfr[nj], acc[mi][nj], 0, 0, 0);
    __syncthreads();
  }
  const float4* ha4 = (const float4*)ha;
  const float4* B4 = (const float4*)Bdn;
#pragma unroll
  for (int nj = 0; nj < 4; ++nj) {
    const int coln = h0 + wc * 64 + nj * 16 + lrow;
    const float4 b0 = B4[coln * 2], b1 = B4[coln * 2 + 1];
#pragma unroll
    for (int mi = 0; mi < 4; ++mi) {
      const int tb = t0 + wr * 64 + mi * 16 + (lane >> 4) * 4;
#pragma unroll
      for (int j = 0; j < 4; ++j) {
        const int t = tb + j;
        const float4 hr0 = ha4[t * 2], hr1 = ha4[t * 2 + 1];
        out[(size_t)t * HH + coln] = acc[mi][nj][j] + SCAL * (dot4(hr0, b0) + dot4(hr1, b1));
      }
    }
  }
}

extern "C" void kernel_launch(void* const* d_in, const int* in_sizes, int n_in,
                              void* d_out, int out_size, void* d_ws, size_t ws_size,
                              hipStream_t stream) {
  const float* x   = (const float*)d_in[0];
  const float* Wgu = (const float*)d_in[1];
  const float* Wdn = (const float*)d_in[2];
  const float* Agu = (const float*)d_in[3];
  const float* Bgu = (const float*)d_in[4];
  const float* Adn = (const float*)d_in[5];
  const float* Bdn = (const float*)d_in[6];
  float* out = (float*)d_out;

  char* ws = (char*)d_ws;
  unsigned short* hidden = (unsigned short*)ws;                      //  32 MB
  const size_t OFF_XB  = (size_t)NROW * II * 2;                      //  32 MB
  const size_t OFF_WGU = OFF_XB + (size_t)NROW * HH * 2;             //  48 MB
  const size_t OFF_WDN = OFF_WGU + (size_t)NE * FF2 * HH * 2;        // 112 MB
  const size_t OFF_XA  = OFF_WDN + (size_t)NE * HH * II * 2;         // 144 MB
  const size_t OFF_HA  = OFF_XA + (size_t)NROW * RR * 4;
  const size_t NEED    = OFF_HA + (size_t)NROW * RR * 4;

  if (ws_size >= NEED) {
    unsigned short* xb   = (unsigned short*)(ws + OFF_XB);
    unsigned short* WguT = (unsigned short*)(ws + OFF_WGU);
    unsigned short* WdnT = (unsigned short*)(ws + OFF_WDN);
    float* xa = (float*)(ws + OFF_XA);
    float* ha = (float*)(ws + OFF_HA);

    convx_kernel<<<(NROW * HH) / (256 * 8), 256, 0, stream>>>(x, xb);
    transconv_gu_kernel<<<NE * 16 * 64, 256, 0, stream>>>(Wgu, WguT);
    transconv_dn_kernel<<<NE * 32 * 16, 256, 0, stream>>>(Wdn, WdnT);
    rowdot_kernel<HH><<<NROW / 4, 256, 0, stream>>>(x, Agu, xa);
    gemm1_8p_kernel<<<NE * 4 * 32, 512, 0, stream>>>(xb, WguT, xa, Bgu, hidden);
    rowdot_bf16_kernel<<<NROW / 4, 256, 0, stream>>>(hidden, Adn, ha);
    gemm2_8p_kernel<<<NE * 4 * 8, 512, 0, stream>>>(hidden, WdnT, ha, Bdn, out);
  } else {
    float* xa = (float*)(ws + OFF_XB);
    float* ha = xa + (size_t)NROW * RR;
    rowdot_kernel<HH><<<NROW / 4, 256, 0, stream>>>(x, Agu, xa);
    gemm1_conv_kernel<<<NE * 8 * 32, 256, 0, stream>>>(x, Wgu, xa, Bgu, hidden);
    rowdot_bf16_kernel<<<NROW / 4, 256, 0, stream>>>(hidden, Adn, ha);
    gemm2_conv_kernel<<<NE * 8 * 8, 256, 0, stream>>>(hidden, Wdn, ha, Bdn, out);
  }
}